// Round 1
// baseline (5446.817 us; speedup 1.0000x reference)
//
#include <hip/hip_runtime.h>
#include <hip/hip_bf16.h>

// Problem constants
#define BB 8
#define SS 512
#define DD 512
#define HH 8
#define DQKv 64
#define DFFv 2048
#define LL 2

// ---------------------------------------------------------------------------
// Sinusoidal positional encoding: pe[s, 2i] = sin(s*div_i), pe[s,2i+1]=cos
// ---------------------------------------------------------------------------
__global__ __launch_bounds__(256) void pe_k(float* __restrict__ pe) {
    int idx = blockIdx.x * 256 + threadIdx.x;   // 0 .. S*256-1
    int s = idx >> 8;
    int i = idx & 255;
    float div = __expf((float)(2 * i) * (-9.210340371976184f / 512.0f));
    float arg = (float)s * div;
    pe[s * DD + 2 * i]     = sinf(arg);
    pe[s * DD + 2 * i + 1] = cosf(arg);
}

// x = in + pe (broadcast over batch), float4 elements
__global__ __launch_bounds__(256) void add_pe_k(const float* __restrict__ in,
                                                const float* __restrict__ pe,
                                                float* __restrict__ out) {
    int i = blockIdx.x * 256 + threadIdx.x;        // over B*S*D/4
    int rem = i & (SS * DD / 4 - 1);               // S*D/4 = 65536 (pow2)
    float4 a = ((const float4*)in)[i];
    float4 p = ((const float4*)pe)[rem];
    a.x += p.x; a.y += p.y; a.z += p.z; a.w += p.w;
    ((float4*)out)[i] = a;
}

__global__ __launch_bounds__(256) void copy_k(const float* __restrict__ in,
                                              float* __restrict__ out) {
    int i = blockIdx.x * 256 + threadIdx.x;
    ((float4*)out)[i] = ((const float4*)in)[i];
}

// ---------------------------------------------------------------------------
// fp32 tiled GEMM: C(M,N) = A(M,K) @ W(K,N) [+bias(N)] [+res(M,N)] [relu]
// 64x64 block tile, BK=16, 256 threads, 4x4 micro-tile.
// M,N,K all multiples of 64/16 in this problem -> no bounds checks.
// ---------------------------------------------------------------------------
template <bool BIAS, bool RES, bool RELU>
__global__ __launch_bounds__(256) void gemm_k(const float* __restrict__ A,
                                              const float* __restrict__ W,
                                              const float* __restrict__ bias,
                                              const float* __restrict__ res,
                                              float* __restrict__ C,
                                              int M, int N, int K) {
    __shared__ float As[16][64];
    __shared__ float Ws[16][64];
    const int tid = threadIdx.x;
    const int ty = tid >> 4, tx = tid & 15;
    const int by = blockIdx.y, bx = blockIdx.x;

    const int ar = tid >> 2;               // 0..63  (A tile row)
    const int ac = (tid & 3) << 2;         // 0,4,8,12 (A tile col group)
    const int wr = tid >> 4;               // 0..15  (W tile row)
    const int wc = (tid & 15) << 2;        // 0..60  (W tile col group)
    const float* Aptr = A + (size_t)(by * 64 + ar) * K + ac;
    const float* Wptr = W + (size_t)wr * N + bx * 64 + wc;

    float acc[4][4] = {};

    for (int k0 = 0; k0 < K; k0 += 16) {
        float4 av = *(const float4*)(Aptr + k0);
        As[ac + 0][ar] = av.x;
        As[ac + 1][ar] = av.y;
        As[ac + 2][ar] = av.z;
        As[ac + 3][ar] = av.w;
        *(float4*)&Ws[wr][wc] = *(const float4*)(Wptr + (size_t)k0 * N);
        __syncthreads();
#pragma unroll
        for (int kk = 0; kk < 16; ++kk) {
            const float4 a = *(const float4*)&As[kk][ty << 2];
            const float4 b = *(const float4*)&Ws[kk][tx << 2];
            acc[0][0] += a.x * b.x; acc[0][1] += a.x * b.y; acc[0][2] += a.x * b.z; acc[0][3] += a.x * b.w;
            acc[1][0] += a.y * b.x; acc[1][1] += a.y * b.y; acc[1][2] += a.y * b.z; acc[1][3] += a.y * b.w;
            acc[2][0] += a.z * b.x; acc[2][1] += a.z * b.y; acc[2][2] += a.z * b.z; acc[2][3] += a.z * b.w;
            acc[3][0] += a.w * b.x; acc[3][1] += a.w * b.y; acc[3][2] += a.w * b.z; acc[3][3] += a.w * b.w;
        }
        __syncthreads();
    }

    const int row0 = by * 64 + (ty << 2);
    const int col0 = bx * 64 + (tx << 2);
    float4 bv = make_float4(0.f, 0.f, 0.f, 0.f);
    if (BIAS) bv = *(const float4*)&bias[col0];
#pragma unroll
    for (int i = 0; i < 4; ++i) {
        float4 c = make_float4(acc[i][0], acc[i][1], acc[i][2], acc[i][3]);
        if (BIAS) { c.x += bv.x; c.y += bv.y; c.z += bv.z; c.w += bv.w; }
        if (RES) {
            const float4 r = *(const float4*)&res[(size_t)(row0 + i) * N + col0];
            c.x += r.x; c.y += r.y; c.z += r.z; c.w += r.w;
        }
        if (RELU) {
            c.x = fmaxf(c.x, 0.f); c.y = fmaxf(c.y, 0.f);
            c.z = fmaxf(c.z, 0.f); c.w = fmaxf(c.w, 0.f);
        }
        *(float4*)&C[(size_t)(row0 + i) * N + col0] = c;
    }
}

// ---------------------------------------------------------------------------
// Attention for one (b, h, 16-query-row tile). Q/K/V stored as (B*S, H*64)
// with head h occupying cols [h*64, h*64+64). Handles windowed masks for
// heads 0..5 (step = 4<<(h>>1)) and key pad mask; softmax matches reference
// (all-masked row -> uniform).
// ---------------------------------------------------------------------------
__global__ __launch_bounds__(256) void attn_k(const float* __restrict__ Q,
                                              const float* __restrict__ Kb,
                                              const float* __restrict__ Vb,
                                              float* __restrict__ O,
                                              const int* __restrict__ pad) {
    __shared__ float sq[16][64];     // scaled Q tile
    __shared__ float skv[64][64];    // K or V staging tile
    __shared__ float sc[16][SS];     // score / prob rows

    const int tid = threadIdx.x;
    const int b = blockIdx.z, h = blockIdx.y, q0 = blockIdx.x << 4;
    const int klim = SS - pad[b];

    // load + scale Q tile
    {
        const int r = tid >> 4, d = (tid & 15) << 2;
        const float4 qv = *(const float4*)&Q[(size_t)(b * SS + q0 + r) * (HH * DQKv) + h * DQKv + d];
        const float s = 0.125f;  // 1/sqrt(64)
        sq[r][d] = qv.x * s; sq[r][d + 1] = qv.y * s;
        sq[r][d + 2] = qv.z * s; sq[r][d + 3] = qv.w * s;
    }

    const int qr = tid >> 4;            // 0..15
    const int kr0 = (tid & 15) << 2;    // 0,4,...,60
    const int qidx = q0 + qr;
    int lo = 0, hi = SS;
    if (h < 6) {
        const int step = 4 << (h >> 1);
        const int s2 = step >> 1;
        const int a1 = (qidx < s2) ? qidx : s2;
        const int a2 = ((SS - 1 - qidx) < s2) ? (SS - 1 - qidx) : s2;
        const int left = (qidx < SS / 2) ? a1 : (step - a2);
        const int right = step - left;
        lo = qidx - left;
        hi = qidx + right;
    }
    __syncthreads();

    // scores
    for (int kt = 0; kt < SS; kt += 64) {
#pragma unroll
        for (int p = 0; p < 4; ++p) {
            const int idx = tid + p * 256;
            const int r = idx >> 4, d = (idx & 15) << 2;
            *(float4*)&skv[r][d] =
                *(const float4*)&Kb[(size_t)(b * SS + kt + r) * (HH * DQKv) + h * DQKv + d];
        }
        __syncthreads();
        float a0 = 0.f, a1 = 0.f, a2 = 0.f, a3 = 0.f;
#pragma unroll
        for (int d = 0; d < 64; d += 4) {
            const float4 qv = *(const float4*)&sq[qr][d];
            const float4 k0v = *(const float4*)&skv[kr0 + 0][d];
            const float4 k1v = *(const float4*)&skv[kr0 + 1][d];
            const float4 k2v = *(const float4*)&skv[kr0 + 2][d];
            const float4 k3v = *(const float4*)&skv[kr0 + 3][d];
            a0 += qv.x * k0v.x + qv.y * k0v.y + qv.z * k0v.z + qv.w * k0v.w;
            a1 += qv.x * k1v.x + qv.y * k1v.y + qv.z * k1v.z + qv.w * k1v.w;
            a2 += qv.x * k2v.x + qv.y * k2v.y + qv.z * k2v.z + qv.w * k2v.w;
            a3 += qv.x * k3v.x + qv.y * k3v.y + qv.z * k3v.z + qv.w * k3v.w;
        }
        float vals[4] = {a0, a1, a2, a3};
#pragma unroll
        for (int j = 0; j < 4; ++j) {
            const int kidx = kt + kr0 + j;
            const bool ok = (kidx < klim) && (kidx >= lo) && (kidx <= hi);
            sc[qr][kidx] = ok ? vals[j] : -1e9f;
        }
        __syncthreads();
    }

    // softmax (4 waves x 4 rows each)
    const int wid = tid >> 6, lane = tid & 63;
#pragma unroll
    for (int rr = 0; rr < 4; ++rr) {
        const int r = wid * 4 + rr;
        float m = -1e30f;
        for (int c = lane; c < SS; c += 64) m = fmaxf(m, sc[r][c]);
#pragma unroll
        for (int off = 32; off; off >>= 1) m = fmaxf(m, __shfl_xor(m, off));
        float sum = 0.f;
        for (int c = lane; c < SS; c += 64) {
            const float e = __expf(sc[r][c] - m);
            sc[r][c] = e;
            sum += e;
        }
#pragma unroll
        for (int off = 32; off; off >>= 1) sum += __shfl_xor(sum, off);
        const float inv = 1.f / sum;
        for (int c = lane; c < SS; c += 64) sc[r][c] *= inv;
    }
    __syncthreads();

    // O = P @ V
    const int dg = (tid & 15) << 2;
    float o0 = 0.f, o1 = 0.f, o2 = 0.f, o3 = 0.f;
    for (int vt = 0; vt < SS; vt += 64) {
#pragma unroll
        for (int p = 0; p < 4; ++p) {
            const int idx = tid + p * 256;
            const int r = idx >> 4, d = (idx & 15) << 2;
            *(float4*)&skv[r][d] =
                *(const float4*)&Vb[(size_t)(b * SS + vt + r) * (HH * DQKv) + h * DQKv + d];
        }
        __syncthreads();
#pragma unroll 8
        for (int kr = 0; kr < 64; ++kr) {
            const float p = sc[qr][vt + kr];
            const float4 vv = *(const float4*)&skv[kr][dg];
            o0 += p * vv.x; o1 += p * vv.y; o2 += p * vv.z; o3 += p * vv.w;
        }
        __syncthreads();
    }
    *(float4*)&O[(size_t)(b * SS + q0 + qr) * (HH * DQKv) + h * DQKv + dg] =
        make_float4(o0, o1, o2, o3);
}

// ---------------------------------------------------------------------------
// LayerNorm over rows of 512: out = (x-mu)/sqrt(var+1e-6)*g + b
// One block (256 threads) per row, 2 elements per thread.
// ---------------------------------------------------------------------------
__global__ __launch_bounds__(256) void ln_k(const float* __restrict__ in,
                                            const float* __restrict__ g,
                                            const float* __restrict__ bvec,
                                            float* __restrict__ out) {
    const int row = blockIdx.x;
    const int tid = threadIdx.x;
    const float2 xv = *(const float2*)&in[(size_t)row * DD + tid * 2];

    __shared__ float red[4];
    __shared__ float red2[4];
    const int wid = tid >> 6, lane = tid & 63;

    float s = xv.x + xv.y;
#pragma unroll
    for (int off = 32; off; off >>= 1) s += __shfl_xor(s, off);
    if (lane == 0) red[wid] = s;
    __syncthreads();
    const float mu = (red[0] + red[1] + red[2] + red[3]) * (1.f / 512.f);

    const float dx = xv.x - mu, dy = xv.y - mu;
    float q = dx * dx + dy * dy;
#pragma unroll
    for (int off = 32; off; off >>= 1) q += __shfl_xor(q, off);
    if (lane == 0) red2[wid] = q;
    __syncthreads();
    const float var = (red2[0] + red2[1] + red2[2] + red2[3]) * (1.f / 512.f);
    const float rs = rsqrtf(var + 1e-6f);

    float2 o;
    o.x = dx * rs * g[tid * 2] + bvec[tid * 2];
    o.y = dy * rs * g[tid * 2 + 1] + bvec[tid * 2 + 1];
    *(float2*)&out[(size_t)row * DD + tid * 2] = o;
}

// ---------------------------------------------------------------------------
// Host orchestration
// ---------------------------------------------------------------------------
extern "C" void kernel_launch(void* const* d_in, const int* in_sizes, int n_in,
                              void* d_out, int out_size, void* d_ws, size_t ws_size,
                              hipStream_t stream) {
    const float* src_seq = (const float*)d_in[0];
    const float* trg_seq = (const float*)d_in[1];
    const int* enc_pad = (const int*)d_in[2];
    const int* dec_pad = (const int*)d_in[3];
    const float* e_wq = (const float*)d_in[4];
    const float* e_wk = (const float*)d_in[5];
    const float* e_wv = (const float*)d_in[6];
    const float* e_wo = (const float*)d_in[7];
    const float* e_g1 = (const float*)d_in[8];
    const float* e_b1 = (const float*)d_in[9];
    const float* e_w1 = (const float*)d_in[10];
    const float* e_bb1 = (const float*)d_in[11];
    const float* e_w2 = (const float*)d_in[12];
    const float* e_bb2 = (const float*)d_in[13];
    const float* e_g2 = (const float*)d_in[14];
    const float* e_b2 = (const float*)d_in[15];
    const float* d_swq = (const float*)d_in[16];
    const float* d_swk = (const float*)d_in[17];
    const float* d_swv = (const float*)d_in[18];
    const float* d_swo = (const float*)d_in[19];
    const float* d_g1 = (const float*)d_in[20];
    const float* d_b1 = (const float*)d_in[21];
    const float* d_cwq = (const float*)d_in[22];
    const float* d_cwk = (const float*)d_in[23];
    const float* d_cwv = (const float*)d_in[24];
    const float* d_cwo = (const float*)d_in[25];
    const float* d_g2 = (const float*)d_in[26];
    const float* d_b2 = (const float*)d_in[27];
    const float* d_w1 = (const float*)d_in[28];
    const float* d_bb1 = (const float*)d_in[29];
    const float* d_w2 = (const float*)d_in[30];
    const float* d_bb2 = (const float*)d_in[31];
    const float* d_g3 = (const float*)d_in[32];
    const float* d_b3 = (const float*)d_in[33];
    (void)in_sizes; (void)n_in; (void)out_size; (void)ws_size;

    const int M = BB * SS;          // 4096
    const int NSD = SS * DD;        // 262144
    const int NTOK = BB * SS * DD;  // 2097152

    float* ws = (float*)d_ws;
    float* pe = ws;
    float* x = pe + NSD;
    float* y = x + NTOK;
    float* bA = y + NTOK;
    float* bB = bA + NTOK;
    float* bC = bB + NTOK;
    float* bD = bC + NTOK;
    float* t0 = bD + NTOK;
    float* hb = bA;  // FFN hidden (4096x2048) spans bA..bD

    pe_k<<<SS, 256, 0, stream>>>(pe);
    add_pe_k<<<NTOK / 4 / 256, 256, 0, stream>>>(src_seq, pe, x);
    add_pe_k<<<NTOK / 4 / 256, 256, 0, stream>>>(trg_seq, pe, y);

    auto do_mha = [&](float* state, const float* kv, const float* wq, const float* wk,
                      const float* wv, const float* wo, const float* g, const float* bb,
                      const int* pad) {
        gemm_k<false, false, false><<<dim3(8, 64), 256, 0, stream>>>(state, wq, nullptr, nullptr, bA, M, 512, 512);
        gemm_k<false, false, false><<<dim3(8, 64), 256, 0, stream>>>(kv, wk, nullptr, nullptr, bB, M, 512, 512);
        gemm_k<false, false, false><<<dim3(8, 64), 256, 0, stream>>>(kv, wv, nullptr, nullptr, bC, M, 512, 512);
        attn_k<<<dim3(SS / 16, HH, BB), 256, 0, stream>>>(bA, bB, bC, bD, pad);
        gemm_k<false, true, false><<<dim3(8, 64), 256, 0, stream>>>(bD, wo, nullptr, state, t0, M, 512, 512);
        ln_k<<<M, 256, 0, stream>>>(t0, g, bb, state);
    };
    auto do_ffn = [&](float* state, const float* w1, const float* b1, const float* w2,
                      const float* b2, const float* g, const float* bb) {
        gemm_k<true, false, true><<<dim3(32, 64), 256, 0, stream>>>(state, w1, b1, nullptr, hb, M, DFFv, 512);
        gemm_k<true, true, false><<<dim3(8, 64), 256, 0, stream>>>(hb, w2, b2, state, t0, M, 512, DFFv);
        ln_k<<<M, 256, 0, stream>>>(t0, g, bb, state);
    };

    for (int l = 0; l < LL; ++l) {
        do_mha(x, x, e_wq + (size_t)l * DD * 512, e_wk + (size_t)l * DD * 512,
               e_wv + (size_t)l * DD * 512, e_wo + (size_t)l * 512 * DD,
               e_g1 + l * DD, e_b1 + l * DD, enc_pad);
        do_ffn(x, e_w1 + (size_t)l * DD * DFFv, e_bb1 + l * DFFv,
               e_w2 + (size_t)l * DFFv * DD, e_bb2 + l * DD,
               e_g2 + l * DD, e_b2 + l * DD);
    }
    for (int l = 0; l < LL; ++l) {
        do_mha(y, y, d_swq + (size_t)l * DD * 512, d_swk + (size_t)l * DD * 512,
               d_swv + (size_t)l * DD * 512, d_swo + (size_t)l * 512 * DD,
               d_g1 + l * DD, d_b1 + l * DD, dec_pad);
        do_mha(y, x, d_cwq + (size_t)l * DD * 512, d_cwk + (size_t)l * DD * 512,
               d_cwv + (size_t)l * DD * 512, d_cwo + (size_t)l * 512 * DD,
               d_g2 + l * DD, d_b2 + l * DD, enc_pad);
        do_ffn(y, d_w1 + (size_t)l * DD * DFFv, d_bb1 + l * DFFv,
               d_w2 + (size_t)l * DFFv * DD, d_bb2 + l * DD,
               d_g3 + l * DD, d_b3 + l * DD);
    }

    copy_k<<<NTOK / 4 / 256, 256, 0, stream>>>(y, (float*)d_out);
}

// Round 2
// 3713.161 us; speedup vs baseline: 1.4669x; 1.4669x over previous
//
#include <hip/hip_runtime.h>
#include <hip/hip_bf16.h>

// Problem constants
#define BB 8
#define SS 512
#define DD 512
#define HH 8
#define DQKv 64
#define DFFv 2048
#define LL 2

// ---------------------------------------------------------------------------
// Sinusoidal positional encoding: pe[s, 2i] = sin(s*div_i), pe[s,2i+1]=cos
// ---------------------------------------------------------------------------
__global__ __launch_bounds__(256) void pe_k(float* __restrict__ pe) {
    int idx = blockIdx.x * 256 + threadIdx.x;   // 0 .. S*256-1
    int s = idx >> 8;
    int i = idx & 255;
    float div = __expf((float)(2 * i) * (-9.210340371976184f / 512.0f));
    float arg = (float)s * div;
    pe[s * DD + 2 * i]     = sinf(arg);
    pe[s * DD + 2 * i + 1] = cosf(arg);
}

// x = in + pe (broadcast over batch), float4 elements
__global__ __launch_bounds__(256) void add_pe_k(const float* __restrict__ in,
                                                const float* __restrict__ pe,
                                                float* __restrict__ out) {
    int i = blockIdx.x * 256 + threadIdx.x;        // over B*S*D/4
    int rem = i & (SS * DD / 4 - 1);               // S*D/4 = 65536 (pow2)
    float4 a = ((const float4*)in)[i];
    float4 p = ((const float4*)pe)[rem];
    a.x += p.x; a.y += p.y; a.z += p.z; a.w += p.w;
    ((float4*)out)[i] = a;
}

__global__ __launch_bounds__(256) void copy_k(const float* __restrict__ in,
                                              float* __restrict__ out) {
    int i = blockIdx.x * 256 + threadIdx.x;
    ((float4*)out)[i] = ((const float4*)in)[i];
}

// ---------------------------------------------------------------------------
// fp32 tiled GEMM: C(M,N) = A(M,K) @ W(K,N) [+bias(N)] [+res(M,N)] [relu]
// 64x64 block tile, BK=16, 256 threads, 4x4 micro-tile.
// ---------------------------------------------------------------------------
template <bool BIAS, bool RES, bool RELU>
__global__ __launch_bounds__(256) void gemm_k(const float* __restrict__ A,
                                              const float* __restrict__ W,
                                              const float* __restrict__ bias,
                                              const float* __restrict__ res,
                                              float* __restrict__ C,
                                              int M, int N, int K) {
    __shared__ float As[16][64];
    __shared__ float Ws[16][64];
    const int tid = threadIdx.x;
    const int ty = tid >> 4, tx = tid & 15;
    const int by = blockIdx.y, bx = blockIdx.x;

    const int ar = tid >> 2;               // 0..63  (A tile row)
    const int ac = (tid & 3) << 2;         // 0,4,8,12 (A tile col group)
    const int wr = tid >> 4;               // 0..15  (W tile row)
    const int wc = (tid & 15) << 2;        // 0..60  (W tile col group)
    const float* Aptr = A + (size_t)(by * 64 + ar) * K + ac;
    const float* Wptr = W + (size_t)wr * N + bx * 64 + wc;

    float acc[4][4] = {};

    for (int k0 = 0; k0 < K; k0 += 16) {
        float4 av = *(const float4*)(Aptr + k0);
        As[ac + 0][ar] = av.x;
        As[ac + 1][ar] = av.y;
        As[ac + 2][ar] = av.z;
        As[ac + 3][ar] = av.w;
        *(float4*)&Ws[wr][wc] = *(const float4*)(Wptr + (size_t)k0 * N);
        __syncthreads();
#pragma unroll
        for (int kk = 0; kk < 16; ++kk) {
            const float4 a = *(const float4*)&As[kk][ty << 2];
            const float4 b = *(const float4*)&Ws[kk][tx << 2];
            acc[0][0] += a.x * b.x; acc[0][1] += a.x * b.y; acc[0][2] += a.x * b.z; acc[0][3] += a.x * b.w;
            acc[1][0] += a.y * b.x; acc[1][1] += a.y * b.y; acc[1][2] += a.y * b.z; acc[1][3] += a.y * b.w;
            acc[2][0] += a.z * b.x; acc[2][1] += a.z * b.y; acc[2][2] += a.z * b.z; acc[2][3] += a.z * b.w;
            acc[3][0] += a.w * b.x; acc[3][1] += a.w * b.y; acc[3][2] += a.w * b.z; acc[3][3] += a.w * b.w;
        }
        __syncthreads();
    }

    const int row0 = by * 64 + (ty << 2);
    const int col0 = bx * 64 + (tx << 2);
    float4 bv = make_float4(0.f, 0.f, 0.f, 0.f);
    if (BIAS) bv = *(const float4*)&bias[col0];
#pragma unroll
    for (int i = 0; i < 4; ++i) {
        float4 c = make_float4(acc[i][0], acc[i][1], acc[i][2], acc[i][3]);
        if (BIAS) { c.x += bv.x; c.y += bv.y; c.z += bv.z; c.w += bv.w; }
        if (RES) {
            const float4 r = *(const float4*)&res[(size_t)(row0 + i) * N + col0];
            c.x += r.x; c.y += r.y; c.z += r.z; c.w += r.w;
        }
        if (RELU) {
            c.x = fmaxf(c.x, 0.f); c.y = fmaxf(c.y, 0.f);
            c.z = fmaxf(c.z, 0.f); c.w = fmaxf(c.w, 0.f);
        }
        *(float4*)&C[(size_t)(row0 + i) * N + col0] = c;
    }
}

// ---------------------------------------------------------------------------
// Attention for one (b, h, 16-query-row tile).
//  - skv padded [64][68] + lane->krow map {a, a+16, a+32, a+48}: conflict-free
//  - windowed heads (h<6, step=4<<(h>>1)): only K-tiles intersecting the
//    tile's window union are processed; softmax/PV restricted to that range.
//  - fallback to full range when an all-masked row is possible
//    (lo(q0+15) >= klim), reproducing reference uniform-over-512 semantics.
// ---------------------------------------------------------------------------
__global__ __launch_bounds__(256) void attn_k(const float* __restrict__ Q,
                                              const float* __restrict__ Kb,
                                              const float* __restrict__ Vb,
                                              float* __restrict__ O,
                                              const int* __restrict__ pad) {
    __shared__ float sq[16][68];     // scaled Q tile (padded)
    __shared__ float skv[64][68];    // K or V staging tile (padded)
    __shared__ float sc[16][520];    // score / prob rows (padded)

    const int tid = threadIdx.x;
    const int b = blockIdx.z, h = blockIdx.y, q0 = blockIdx.x << 4;
    const int klim = SS - pad[b];

    const int qr = tid >> 4;            // 0..15 (query row in tile)
    const int a = tid & 15;             // 0..15 (k-row group / d-group)

    // load + scale Q tile
    {
        const int r = tid >> 4, d = (tid & 15) << 2;
        const float4 qv = *(const float4*)&Q[(size_t)(b * SS + q0 + r) * (HH * DQKv) + h * DQKv + d];
        const float s = 0.125f;  // 1/sqrt(64)
        sq[r][d] = qv.x * s; sq[r][d + 1] = qv.y * s;
        sq[r][d + 2] = qv.z * s; sq[r][d + 3] = qv.w * s;
    }

    // window bounds for a query index
    auto window = [&](int i, int& wlo, int& whi) {
        if (h < 6) {
            const int step = 4 << (h >> 1);
            const int s2 = step >> 1;
            const int a1 = (i < s2) ? i : s2;
            const int a2 = ((SS - 1 - i) < s2) ? (SS - 1 - i) : s2;
            const int left = (i < SS / 2) ? a1 : (step - a2);
            wlo = i - left;
            whi = wlo + step;
        } else {
            wlo = 0;
            whi = SS - 1;
        }
    };
    int lo, hi;
    window(q0 + qr, lo, hi);

    int kt0 = 0, kt1 = SS;
    if (h < 6) {
        int lo0, hi0, lo15, hi15;
        window(q0, lo0, hi0);
        window(q0 + 15, lo15, hi15);
        if (lo15 >= klim) {
            kt0 = 0; kt1 = SS;          // all-masked row possible -> full range
        } else {
            kt0 = (lo0 >> 6) << 6;
            kt1 = ((hi15 >> 6) + 1) << 6;
        }
    }
    __syncthreads();

    // ---- scores over [kt0, kt1) ----
    for (int kt = kt0; kt < kt1; kt += 64) {
#pragma unroll
        for (int p = 0; p < 4; ++p) {
            const int idx = tid + p * 256;
            const int r = idx >> 4, d = (idx & 15) << 2;
            *(float4*)&skv[r][d] =
                *(const float4*)&Kb[(size_t)(b * SS + kt + r) * (HH * DQKv) + h * DQKv + d];
        }
        __syncthreads();
        float a0 = 0.f, a1 = 0.f, a2 = 0.f, a3 = 0.f;
#pragma unroll
        for (int d0 = 0; d0 < 64; d0 += 4) {
            const float4 qv = *(const float4*)&sq[qr][d0];
            const float4 k0v = *(const float4*)&skv[a][d0];
            const float4 k1v = *(const float4*)&skv[a + 16][d0];
            const float4 k2v = *(const float4*)&skv[a + 32][d0];
            const float4 k3v = *(const float4*)&skv[a + 48][d0];
            a0 += qv.x * k0v.x + qv.y * k0v.y + qv.z * k0v.z + qv.w * k0v.w;
            a1 += qv.x * k1v.x + qv.y * k1v.y + qv.z * k1v.z + qv.w * k1v.w;
            a2 += qv.x * k2v.x + qv.y * k2v.y + qv.z * k2v.z + qv.w * k2v.w;
            a3 += qv.x * k3v.x + qv.y * k3v.y + qv.z * k3v.z + qv.w * k3v.w;
        }
        const float vals[4] = {a0, a1, a2, a3};
#pragma unroll
        for (int jj = 0; jj < 4; ++jj) {
            const int kidx = kt + a + 16 * jj;
            const bool ok = (kidx < klim) && (kidx >= lo) && (kidx <= hi);
            sc[qr][kidx] = ok ? vals[jj] : -1e9f;
        }
        __syncthreads();
    }

    // ---- softmax over [kt0, kt1) (4 waves x 4 rows each) ----
    const int wid = tid >> 6, lane = tid & 63;
    const int nc = kt1 - kt0;   // multiple of 64
#pragma unroll
    for (int rr = 0; rr < 4; ++rr) {
        const int r = wid * 4 + rr;
        float m = -1e30f;
        for (int c = lane; c < nc; c += 64) m = fmaxf(m, sc[r][kt0 + c]);
#pragma unroll
        for (int off = 32; off; off >>= 1) m = fmaxf(m, __shfl_xor(m, off));
        float sum = 0.f;
        for (int c = lane; c < nc; c += 64) {
            const float e = __expf(sc[r][kt0 + c] - m);
            sc[r][kt0 + c] = e;
            sum += e;
        }
#pragma unroll
        for (int off = 32; off; off >>= 1) sum += __shfl_xor(sum, off);
        const float inv = 1.f / sum;
        for (int c = lane; c < nc; c += 64) sc[r][kt0 + c] *= inv;
    }
    __syncthreads();

    // ---- O = P @ V over [kt0, kt1) ----
    const int dg = a << 2;
    float o0 = 0.f, o1 = 0.f, o2 = 0.f, o3 = 0.f;
    for (int vt = kt0; vt < kt1; vt += 64) {
#pragma unroll
        for (int p = 0; p < 4; ++p) {
            const int idx = tid + p * 256;
            const int r = idx >> 4, d = (idx & 15) << 2;
            *(float4*)&skv[r][d] =
                *(const float4*)&Vb[(size_t)(b * SS + vt + r) * (HH * DQKv) + h * DQKv + d];
        }
        __syncthreads();
#pragma unroll 8
        for (int kr = 0; kr < 64; ++kr) {
            const float p = sc[qr][vt + kr];
            const float4 vv = *(const float4*)&skv[kr][dg];
            o0 += p * vv.x; o1 += p * vv.y; o2 += p * vv.z; o3 += p * vv.w;
        }
        __syncthreads();
    }
    *(float4*)&O[(size_t)(b * SS + q0 + qr) * (HH * DQKv) + h * DQKv + dg] =
        make_float4(o0, o1, o2, o3);
}

// ---------------------------------------------------------------------------
// LayerNorm over rows of 512: out = (x-mu)/sqrt(var+1e-6)*g + b
// ---------------------------------------------------------------------------
__global__ __launch_bounds__(256) void ln_k(const float* __restrict__ in,
                                            const float* __restrict__ g,
                                            const float* __restrict__ bvec,
                                            float* __restrict__ out) {
    const int row = blockIdx.x;
    const int tid = threadIdx.x;
    const float2 xv = *(const float2*)&in[(size_t)row * DD + tid * 2];

    __shared__ float red[4];
    __shared__ float red2[4];
    const int wid = tid >> 6, lane = tid & 63;

    float s = xv.x + xv.y;
#pragma unroll
    for (int off = 32; off; off >>= 1) s += __shfl_xor(s, off);
    if (lane == 0) red[wid] = s;
    __syncthreads();
    const float mu = (red[0] + red[1] + red[2] + red[3]) * (1.f / 512.f);

    const float dx = xv.x - mu, dy = xv.y - mu;
    float q = dx * dx + dy * dy;
#pragma unroll
    for (int off = 32; off; off >>= 1) q += __shfl_xor(q, off);
    if (lane == 0) red2[wid] = q;
    __syncthreads();
    const float var = (red2[0] + red2[1] + red2[2] + red2[3]) * (1.f / 512.f);
    const float rs = rsqrtf(var + 1e-6f);

    float2 o;
    o.x = dx * rs * g[tid * 2] + bvec[tid * 2];
    o.y = dy * rs * g[tid * 2 + 1] + bvec[tid * 2 + 1];
    *(float2*)&out[(size_t)row * DD + tid * 2] = o;
}

// ---------------------------------------------------------------------------
// Host orchestration
// ---------------------------------------------------------------------------
extern "C" void kernel_launch(void* const* d_in, const int* in_sizes, int n_in,
                              void* d_out, int out_size, void* d_ws, size_t ws_size,
                              hipStream_t stream) {
    const float* src_seq = (const float*)d_in[0];
    const float* trg_seq = (const float*)d_in[1];
    const int* enc_pad = (const int*)d_in[2];
    const int* dec_pad = (const int*)d_in[3];
    const float* e_wq = (const float*)d_in[4];
    const float* e_wk = (const float*)d_in[5];
    const float* e_wv = (const float*)d_in[6];
    const float* e_wo = (const float*)d_in[7];
    const float* e_g1 = (const float*)d_in[8];
    const float* e_b1 = (const float*)d_in[9];
    const float* e_w1 = (const float*)d_in[10];
    const float* e_bb1 = (const float*)d_in[11];
    const float* e_w2 = (const float*)d_in[12];
    const float* e_bb2 = (const float*)d_in[13];
    const float* e_g2 = (const float*)d_in[14];
    const float* e_b2 = (const float*)d_in[15];
    const float* d_swq = (const float*)d_in[16];
    const float* d_swk = (const float*)d_in[17];
    const float* d_swv = (const float*)d_in[18];
    const float* d_swo = (const float*)d_in[19];
    const float* d_g1 = (const float*)d_in[20];
    const float* d_b1 = (const float*)d_in[21];
    const float* d_cwq = (const float*)d_in[22];
    const float* d_cwk = (const float*)d_in[23];
    const float* d_cwv = (const float*)d_in[24];
    const float* d_cwo = (const float*)d_in[25];
    const float* d_g2 = (const float*)d_in[26];
    const float* d_b2 = (const float*)d_in[27];
    const float* d_w1 = (const float*)d_in[28];
    const float* d_bb1 = (const float*)d_in[29];
    const float* d_w2 = (const float*)d_in[30];
    const float* d_bb2 = (const float*)d_in[31];
    const float* d_g3 = (const float*)d_in[32];
    const float* d_b3 = (const float*)d_in[33];
    (void)in_sizes; (void)n_in; (void)out_size; (void)ws_size;

    const int M = BB * SS;          // 4096
    const int NSD = SS * DD;        // 262144
    const int NTOK = BB * SS * DD;  // 2097152

    float* ws = (float*)d_ws;
    float* pe = ws;
    float* x = pe + NSD;
    float* y = x + NTOK;
    float* bA = y + NTOK;
    float* bB = bA + NTOK;
    float* bC = bB + NTOK;
    float* bD = bC + NTOK;
    float* t0 = bD + NTOK;
    float* hb = bA;  // FFN hidden (4096x2048) spans bA..bD

    pe_k<<<SS, 256, 0, stream>>>(pe);
    add_pe_k<<<NTOK / 4 / 256, 256, 0, stream>>>(src_seq, pe, x);
    add_pe_k<<<NTOK / 4 / 256, 256, 0, stream>>>(trg_seq, pe, y);

    auto do_mha = [&](float* state, const float* kv, const float* wq, const float* wk,
                      const float* wv, const float* wo, const float* g, const float* bb,
                      const int* pad) {
        gemm_k<false, false, false><<<dim3(8, 64), 256, 0, stream>>>(state, wq, nullptr, nullptr, bA, M, 512, 512);
        gemm_k<false, false, false><<<dim3(8, 64), 256, 0, stream>>>(kv, wk, nullptr, nullptr, bB, M, 512, 512);
        gemm_k<false, false, false><<<dim3(8, 64), 256, 0, stream>>>(kv, wv, nullptr, nullptr, bC, M, 512, 512);
        attn_k<<<dim3(SS / 16, HH, BB), 256, 0, stream>>>(bA, bB, bC, bD, pad);
        gemm_k<false, true, false><<<dim3(8, 64), 256, 0, stream>>>(bD, wo, nullptr, state, t0, M, 512, 512);
        ln_k<<<M, 256, 0, stream>>>(t0, g, bb, state);
    };
    auto do_ffn = [&](float* state, const float* w1, const float* b1, const float* w2,
                      const float* b2, const float* g, const float* bb) {
        gemm_k<true, false, true><<<dim3(32, 64), 256, 0, stream>>>(state, w1, b1, nullptr, hb, M, DFFv, 512);
        gemm_k<true, true, false><<<dim3(8, 64), 256, 0, stream>>>(hb, w2, b2, state, t0, M, 512, DFFv);
        ln_k<<<M, 256, 0, stream>>>(t0, g, bb, state);
    };

    for (int l = 0; l < LL; ++l) {
        do_mha(x, x, e_wq + (size_t)l * DD * 512, e_wk + (size_t)l * DD * 512,
               e_wv + (size_t)l * DD * 512, e_wo + (size_t)l * 512 * DD,
               e_g1 + l * DD, e_b1 + l * DD, enc_pad);
        do_ffn(x, e_w1 + (size_t)l * DD * DFFv, e_bb1 + l * DFFv,
               e_w2 + (size_t)l * DFFv * DD, e_bb2 + l * DD,
               e_g2 + l * DD, e_b2 + l * DD);
    }
    for (int l = 0; l < LL; ++l) {
        do_mha(y, y, d_swq + (size_t)l * DD * 512, d_swk + (size_t)l * DD * 512,
               d_swv + (size_t)l * DD * 512, d_swo + (size_t)l * 512 * DD,
               d_g1 + l * DD, d_b1 + l * DD, dec_pad);
        do_mha(y, x, d_cwq + (size_t)l * DD * 512, d_cwk + (size_t)l * DD * 512,
               d_cwv + (size_t)l * DD * 512, d_cwo + (size_t)l * 512 * DD,
               d_g2 + l * DD, d_b2 + l * DD, enc_pad);
        do_ffn(y, d_w1 + (size_t)l * DD * DFFv, d_bb1 + l * DFFv,
               d_w2 + (size_t)l * DFFv * DD, d_bb2 + l * DD,
               d_g3 + l * DD, d_b3 + l * DD);
    }

    copy_k<<<NTOK / 4 / 256, 256, 0, stream>>>(y, (float*)d_out);
}

// Round 3
// 1285.384 us; speedup vs baseline: 4.2375x; 2.8888x over previous
//
#include <hip/hip_runtime.h>
#include <hip/hip_bf16.h>

// Problem constants
#define BB 8
#define SS 512
#define DD 512
#define HH 8
#define DQKv 64
#define DFFv 2048
#define LL 2

typedef __attribute__((ext_vector_type(8))) __bf16 bf16x8;
typedef __attribute__((ext_vector_type(4))) float f32x4;

// fp32 -> bf16 (RNE), bf16 -> fp32 helpers on raw ushort bits
static __device__ __forceinline__ ushort f2b(float x) {
    unsigned int u = __float_as_uint(x);
    unsigned int r = (u + 0x7FFFu + ((u >> 16) & 1u)) >> 16;
    return (ushort)r;
}
static __device__ __forceinline__ float b2f(ushort u) {
    return __uint_as_float(((unsigned int)u) << 16);
}

// ---------------------------------------------------------------------------
// Sinusoidal positional encoding
// ---------------------------------------------------------------------------
__global__ __launch_bounds__(256) void pe_k(float* __restrict__ pe) {
    int idx = blockIdx.x * 256 + threadIdx.x;
    int s = idx >> 8;
    int i = idx & 255;
    float div = __expf((float)(2 * i) * (-9.210340371976184f / 512.0f));
    float arg = (float)s * div;
    pe[s * DD + 2 * i]     = sinf(arg);
    pe[s * DD + 2 * i + 1] = cosf(arg);
}

// x = in + pe (broadcast over batch); writes fp32 + bf16 copies
__global__ __launch_bounds__(256) void add_pe_k(const float* __restrict__ in,
                                                const float* __restrict__ pe,
                                                float* __restrict__ outf,
                                                ushort* __restrict__ outb) {
    int i = blockIdx.x * 256 + threadIdx.x;        // over B*S*D/4
    int rem = i & (SS * DD / 4 - 1);
    float4 a = ((const float4*)in)[i];
    float4 p = ((const float4*)pe)[rem];
    a.x += p.x; a.y += p.y; a.z += p.z; a.w += p.w;
    ((float4*)outf)[i] = a;
    ushort4 ub;
    ub.x = f2b(a.x); ub.y = f2b(a.y); ub.z = f2b(a.z); ub.w = f2b(a.w);
    ((ushort4*)outb)[i] = ub;
}

__global__ __launch_bounds__(256) void copy_k(const float* __restrict__ in,
                                              float* __restrict__ out) {
    int i = blockIdx.x * 256 + threadIdx.x;
    ((float4*)out)[i] = ((const float4*)in)[i];
}

// ---------------------------------------------------------------------------
// Weight transpose + cast: src (K x N fp32, pick by blockIdx.z) -> dst (N x K bf16)
// ---------------------------------------------------------------------------
__global__ __launch_bounds__(256) void tcast_k(const float* __restrict__ s0,
                                               const float* __restrict__ s1,
                                               const float* __restrict__ s2,
                                               const float* __restrict__ s3,
                                               ushort* __restrict__ dst,
                                               int K, int N) {
    __shared__ ushort st[64][72];
    const float* src = (blockIdx.z == 0) ? s0 : (blockIdx.z == 1) ? s1
                     : (blockIdx.z == 2) ? s2 : s3;
    ushort* d = dst + (size_t)blockIdx.z * K * N;
    const int k0 = blockIdx.y * 64, n0 = blockIdx.x * 64;
    const int t = threadIdx.x;
    const int r = t >> 2, c4 = (t & 3) * 16;
#pragma unroll
    for (int i = 0; i < 16; i += 4) {
        float4 v = *(const float4*)&src[(size_t)(k0 + r) * N + n0 + c4 + i];
        st[c4 + i + 0][r] = f2b(v.x);
        st[c4 + i + 1][r] = f2b(v.y);
        st[c4 + i + 2][r] = f2b(v.z);
        st[c4 + i + 3][r] = f2b(v.w);
    }
    __syncthreads();
    const int n = t >> 2, seg = (t & 3) * 16;
    *(uint4*)&d[(size_t)(n0 + n) * K + k0 + seg]     = *(const uint4*)&st[n][seg];
    *(uint4*)&d[(size_t)(n0 + n) * K + k0 + seg + 8] = *(const uint4*)&st[n][seg + 8];
}

// ---------------------------------------------------------------------------
// bf16 MFMA GEMM: C(M,N) = A(M,K) @ Bt(N,K)^T  [+bias] [+res] [relu]
// 64x64 tile, BK=64, 256 threads (4 waves), each wave 32x32 via 2x2 16x16x32.
// ---------------------------------------------------------------------------
template <bool BIAS, bool RES, bool RELU, bool OUTBF>
__global__ __launch_bounds__(256) void gemm_mfma_k(const ushort* __restrict__ A,
                                                   const ushort* __restrict__ Bt,
                                                   const float* __restrict__ bias,
                                                   const float* __restrict__ res,
                                                   void* __restrict__ Cout,
                                                   int M, int N, int K) {
    __shared__ ushort As[64][72];
    __shared__ ushort Bs[64][72];
    const int tid = threadIdx.x;
    const int bx = blockIdx.x, by = blockIdx.y;
    const int lane = tid & 63, w = tid >> 6;
    const int rw = (w >> 1) * 32, cw = (w & 1) * 32;

    const int srow = tid >> 2;          // 0..63
    const int sseg = (tid & 3) * 16;    // ushort offset within row
    const ushort* Ap = A + (size_t)(by * 64 + srow) * K + sseg;
    const ushort* Bp = Bt + (size_t)(bx * 64 + srow) * K + sseg;

    f32x4 acc[2][2] = {};

    const int lrow = lane & 15;
    const int lk = (lane >> 4) * 8;

    for (int k0 = 0; k0 < K; k0 += 64) {
        *(uint4*)&As[srow][sseg]     = *(const uint4*)(Ap + k0);
        *(uint4*)&As[srow][sseg + 8] = *(const uint4*)(Ap + k0 + 8);
        *(uint4*)&Bs[srow][sseg]     = *(const uint4*)(Bp + k0);
        *(uint4*)&Bs[srow][sseg + 8] = *(const uint4*)(Bp + k0 + 8);
        __syncthreads();
#pragma unroll
        for (int ks = 0; ks < 2; ++ks) {
            bf16x8 a0 = *(const bf16x8*)&As[rw + lrow][ks * 32 + lk];
            bf16x8 a1 = *(const bf16x8*)&As[rw + 16 + lrow][ks * 32 + lk];
            bf16x8 b0 = *(const bf16x8*)&Bs[cw + lrow][ks * 32 + lk];
            bf16x8 b1 = *(const bf16x8*)&Bs[cw + 16 + lrow][ks * 32 + lk];
            acc[0][0] = __builtin_amdgcn_mfma_f32_16x16x32_bf16(a0, b0, acc[0][0], 0, 0, 0);
            acc[0][1] = __builtin_amdgcn_mfma_f32_16x16x32_bf16(a0, b1, acc[0][1], 0, 0, 0);
            acc[1][0] = __builtin_amdgcn_mfma_f32_16x16x32_bf16(a1, b0, acc[1][0], 0, 0, 0);
            acc[1][1] = __builtin_amdgcn_mfma_f32_16x16x32_bf16(a1, b1, acc[1][1], 0, 0, 0);
        }
        __syncthreads();
    }

    // Epilogue. C/D frag: col = lane&15, row = (lane>>4)*4 + j  [verified m89]
    const int crow0 = by * 64 + rw + (lane >> 4) * 4;
    const int ccol0 = bx * 64 + cw + lrow;
#pragma unroll
    for (int m = 0; m < 2; ++m) {
#pragma unroll
        for (int n = 0; n < 2; ++n) {
            const int col = ccol0 + n * 16;
            const float bv = BIAS ? bias[col] : 0.f;
#pragma unroll
            for (int j = 0; j < 4; ++j) {
                const int row = crow0 + m * 16 + j;
                float v = acc[m][n][j] + bv;
                if (RES) v += res[(size_t)row * N + col];
                if (RELU) v = fmaxf(v, 0.f);
                if (OUTBF) ((ushort*)Cout)[(size_t)row * N + col] = f2b(v);
                else       ((float*)Cout)[(size_t)row * N + col] = v;
            }
        }
    }
}

// ---------------------------------------------------------------------------
// Flash attention for one (b, h, 16-query-row tile). Q/K/V/O bf16.
// Online softmax (running m, l) -> no full score row in LDS.
// Windowed heads restricted to [kt0,kt1); fallback to full range when an
// all-masked row is possible (reproduces reference uniform-over-512).
// ---------------------------------------------------------------------------
__global__ __launch_bounds__(256) void attn_k(const ushort* __restrict__ Q,
                                              const ushort* __restrict__ Kb,
                                              const ushort* __restrict__ Vb,
                                              ushort* __restrict__ O,
                                              const int* __restrict__ pad) {
    __shared__ float sq[16][68];     // scaled Q tile
    __shared__ float skv[64][68];    // K or V staging tile
    __shared__ float sp[16][68];     // probabilities for current tile

    const int tid = threadIdx.x;
    const int b = blockIdx.z, h = blockIdx.y, q0 = blockIdx.x << 4;
    const int klim = SS - pad[b];

    const int qr = tid >> 4;            // 0..15
    const int a = tid & 15;             // 0..15

    // load + scale Q tile (bf16 -> fp32)
    {
        const int d = a << 2;
        const ushort4 qv = *(const ushort4*)&Q[(size_t)(b * SS + q0 + qr) * (HH * DQKv) + h * DQKv + d];
        const float s = 0.125f;
        sq[qr][d + 0] = b2f(qv.x) * s;
        sq[qr][d + 1] = b2f(qv.y) * s;
        sq[qr][d + 2] = b2f(qv.z) * s;
        sq[qr][d + 3] = b2f(qv.w) * s;
    }

    auto window = [&](int i, int& wlo, int& whi) {
        if (h < 6) {
            const int step = 4 << (h >> 1);
            const int s2 = step >> 1;
            const int a1 = (i < s2) ? i : s2;
            const int a2 = ((SS - 1 - i) < s2) ? (SS - 1 - i) : s2;
            const int left = (i < SS / 2) ? a1 : (step - a2);
            wlo = i - left;
            whi = wlo + step;
        } else {
            wlo = 0;
            whi = SS - 1;
        }
    };
    int lo, hi;
    window(q0 + qr, lo, hi);

    int kt0 = 0, kt1 = SS;
    if (h < 6) {
        int lo0, hi0, lo15, hi15;
        window(q0, lo0, hi0);
        window(q0 + 15, lo15, hi15);
        if (lo15 >= klim) {
            kt0 = 0; kt1 = SS;          // all-masked row possible -> full range
        } else {
            kt0 = (lo0 >> 6) << 6;
            kt1 = ((hi15 >> 6) + 1) << 6;
        }
    }
    __syncthreads();

    float m = -1e30f, l = 0.f;
    float o0 = 0.f, o1 = 0.f, o2 = 0.f, o3 = 0.f;
    const int dg = a << 2;

    for (int kt = kt0; kt < kt1; kt += 64) {
        // ---- stage K tile ----
#pragma unroll
        for (int p = 0; p < 4; ++p) {
            const int idx = tid + p * 256;
            const int r = idx >> 4, d = (idx & 15) << 2;
            const ushort4 kv = *(const ushort4*)&Kb[(size_t)(b * SS + kt + r) * (HH * DQKv) + h * DQKv + d];
            skv[r][d + 0] = b2f(kv.x); skv[r][d + 1] = b2f(kv.y);
            skv[r][d + 2] = b2f(kv.z); skv[r][d + 3] = b2f(kv.w);
        }
        __syncthreads();

        // ---- scores for keys a, a+16, a+32, a+48 ----
        float s0 = 0.f, s1 = 0.f, s2 = 0.f, s3 = 0.f;
#pragma unroll
        for (int d0 = 0; d0 < 64; d0 += 4) {
            const float4 qv  = *(const float4*)&sq[qr][d0];
            const float4 k0v = *(const float4*)&skv[a][d0];
            const float4 k1v = *(const float4*)&skv[a + 16][d0];
            const float4 k2v = *(const float4*)&skv[a + 32][d0];
            const float4 k3v = *(const float4*)&skv[a + 48][d0];
            s0 += qv.x * k0v.x + qv.y * k0v.y + qv.z * k0v.z + qv.w * k0v.w;
            s1 += qv.x * k1v.x + qv.y * k1v.y + qv.z * k1v.z + qv.w * k1v.w;
            s2 += qv.x * k2v.x + qv.y * k2v.y + qv.z * k2v.z + qv.w * k2v.w;
            s3 += qv.x * k3v.x + qv.y * k3v.y + qv.z * k3v.z + qv.w * k3v.w;
        }
        {
            const int k0i = kt + a, k1i = kt + a + 16, k2i = kt + a + 32, k3i = kt + a + 48;
            s0 = ((k0i < klim) && (k0i >= lo) && (k0i <= hi)) ? s0 : -1e9f;
            s1 = ((k1i < klim) && (k1i >= lo) && (k1i <= hi)) ? s1 : -1e9f;
            s2 = ((k2i < klim) && (k2i >= lo) && (k2i <= hi)) ? s2 : -1e9f;
            s3 = ((k3i < klim) && (k3i >= lo) && (k3i <= hi)) ? s3 : -1e9f;
        }

        // ---- online softmax update (row = 16-lane group) ----
        float tm = fmaxf(fmaxf(s0, s1), fmaxf(s2, s3));
#pragma unroll
        for (int off = 8; off; off >>= 1) tm = fmaxf(tm, __shfl_xor(tm, off));
        const float mn = fmaxf(m, tm);
        const float alpha = __expf(m - mn);
        const float p0 = __expf(s0 - mn), p1 = __expf(s1 - mn);
        const float p2 = __expf(s2 - mn), p3 = __expf(s3 - mn);
        float ps = p0 + p1 + p2 + p3;
#pragma unroll
        for (int off = 8; off; off >>= 1) ps += __shfl_xor(ps, off);
        l = l * alpha + ps;
        m = mn;
        o0 *= alpha; o1 *= alpha; o2 *= alpha; o3 *= alpha;
        sp[qr][a] = p0; sp[qr][a + 16] = p1; sp[qr][a + 32] = p2; sp[qr][a + 48] = p3;
        __syncthreads();   // K reads + sp writes done before V overwrite

        // ---- stage V tile (over skv) ----
#pragma unroll
        for (int p = 0; p < 4; ++p) {
            const int idx = tid + p * 256;
            const int r = idx >> 4, d = (idx & 15) << 2;
            const ushort4 vv = *(const ushort4*)&Vb[(size_t)(b * SS + kt + r) * (HH * DQKv) + h * DQKv + d];
            skv[r][d + 0] = b2f(vv.x); skv[r][d + 1] = b2f(vv.y);
            skv[r][d + 2] = b2f(vv.z); skv[r][d + 3] = b2f(vv.w);
        }
        __syncthreads();

        // ---- PV accumulate ----
#pragma unroll 8
        for (int kr = 0; kr < 64; ++kr) {
            const float p = sp[qr][kr];
            const float4 vv = *(const float4*)&skv[kr][dg];
            o0 += p * vv.x; o1 += p * vv.y; o2 += p * vv.z; o3 += p * vv.w;
        }
        __syncthreads();   // PV reads done before next K stage
    }

    const float inv = 1.f / l;
    ushort4 ov;
    ov.x = f2b(o0 * inv); ov.y = f2b(o1 * inv);
    ov.z = f2b(o2 * inv); ov.w = f2b(o3 * inv);
    *(ushort4*)&O[(size_t)(b * SS + q0 + qr) * (HH * DQKv) + h * DQKv + dg] = ov;
}

// ---------------------------------------------------------------------------
// LayerNorm over rows of 512; writes fp32 state + bf16 state copy
// ---------------------------------------------------------------------------
__global__ __launch_bounds__(256) void ln_k(const float* __restrict__ in,
                                            const float* __restrict__ g,
                                            const float* __restrict__ bvec,
                                            float* __restrict__ outf,
                                            ushort* __restrict__ outb) {
    const int row = blockIdx.x;
    const int tid = threadIdx.x;
    const float2 xv = *(const float2*)&in[(size_t)row * DD + tid * 2];

    __shared__ float red[4];
    __shared__ float red2[4];
    const int wid = tid >> 6, lane = tid & 63;

    float s = xv.x + xv.y;
#pragma unroll
    for (int off = 32; off; off >>= 1) s += __shfl_xor(s, off);
    if (lane == 0) red[wid] = s;
    __syncthreads();
    const float mu = (red[0] + red[1] + red[2] + red[3]) * (1.f / 512.f);

    const float dx = xv.x - mu, dy = xv.y - mu;
    float q = dx * dx + dy * dy;
#pragma unroll
    for (int off = 32; off; off >>= 1) q += __shfl_xor(q, off);
    if (lane == 0) red2[wid] = q;
    __syncthreads();
    const float var = (red2[0] + red2[1] + red2[2] + red2[3]) * (1.f / 512.f);
    const float rs = rsqrtf(var + 1e-6f);

    float2 o;
    o.x = dx * rs * g[tid * 2] + bvec[tid * 2];
    o.y = dy * rs * g[tid * 2 + 1] + bvec[tid * 2 + 1];
    *(float2*)&outf[(size_t)row * DD + tid * 2] = o;
    ushort2 ub; ub.x = f2b(o.x); ub.y = f2b(o.y);
    *(ushort2*)&outb[(size_t)row * DD + tid * 2] = ub;
}

// ---------------------------------------------------------------------------
// Host orchestration
// ---------------------------------------------------------------------------
extern "C" void kernel_launch(void* const* d_in, const int* in_sizes, int n_in,
                              void* d_out, int out_size, void* d_ws, size_t ws_size,
                              hipStream_t stream) {
    const float* src_seq = (const float*)d_in[0];
    const float* trg_seq = (const float*)d_in[1];
    const int* enc_pad = (const int*)d_in[2];
    const int* dec_pad = (const int*)d_in[3];
    const float* e_wq = (const float*)d_in[4];
    const float* e_wk = (const float*)d_in[5];
    const float* e_wv = (const float*)d_in[6];
    const float* e_wo = (const float*)d_in[7];
    const float* e_g1 = (const float*)d_in[8];
    const float* e_b1 = (const float*)d_in[9];
    const float* e_w1 = (const float*)d_in[10];
    const float* e_bb1 = (const float*)d_in[11];
    const float* e_w2 = (const float*)d_in[12];
    const float* e_bb2 = (const float*)d_in[13];
    const float* e_g2 = (const float*)d_in[14];
    const float* e_b2 = (const float*)d_in[15];
    const float* d_swq = (const float*)d_in[16];
    const float* d_swk = (const float*)d_in[17];
    const float* d_swv = (const float*)d_in[18];
    const float* d_swo = (const float*)d_in[19];
    const float* d_g1 = (const float*)d_in[20];
    const float* d_b1 = (const float*)d_in[21];
    const float* d_cwq = (const float*)d_in[22];
    const float* d_cwk = (const float*)d_in[23];
    const float* d_cwv = (const float*)d_in[24];
    const float* d_cwo = (const float*)d_in[25];
    const float* d_g2 = (const float*)d_in[26];
    const float* d_b2 = (const float*)d_in[27];
    const float* d_w1 = (const float*)d_in[28];
    const float* d_bb1 = (const float*)d_in[29];
    const float* d_w2 = (const float*)d_in[30];
    const float* d_bb2 = (const float*)d_in[31];
    const float* d_g3 = (const float*)d_in[32];
    const float* d_b3 = (const float*)d_in[33];
    (void)in_sizes; (void)n_in; (void)out_size; (void)ws_size;

    const int M = BB * SS;          // 4096
    const int NSD = SS * DD;        // 262144
    const int NTOK = BB * SS * DD;  // 2097152
    const size_t WSZ = (size_t)DD * 512;  // 262144 (one 512x512 weight)

    float* ws = (float*)d_ws;
    float* pe = ws;
    float* x  = pe + NSD;
    float* y  = x + NTOK;
    float* t0 = y + NTOK;
    ushort* xbf = (ushort*)(t0 + NTOK);
    ushort* ybf = xbf + NTOK;
    ushort* qb  = ybf + NTOK;
    ushort* kb  = qb + NTOK;
    ushort* vb  = kb + NTOK;
    ushort* ob  = vb + NTOK;
    ushort* hbf = qb;               // FFN hidden (4096x2048 bf16) aliases qb..ob
    ushort* wt  = ob + NTOK;        // 1M bf16 transposed-weight scratch (2 MB)

    pe_k<<<SS, 256, 0, stream>>>(pe);
    add_pe_k<<<NTOK / 4 / 256, 256, 0, stream>>>(src_seq, pe, x, xbf);
    add_pe_k<<<NTOK / 4 / 256, 256, 0, stream>>>(trg_seq, pe, y, ybf);

    // statef/statebf: residual stream; qsrc/kvsrc: bf16 GEMM inputs
    auto do_mha = [&](float* statef, ushort* statebf, const ushort* kvbf,
                      const float* wq, const float* wk, const float* wv, const float* wo,
                      const float* g, const float* bb, const int* pad) {
        tcast_k<<<dim3(8, 8, 4), 256, 0, stream>>>(wq, wk, wv, wo, wt, 512, 512);
        gemm_mfma_k<false, false, false, true><<<dim3(8, 64), 256, 0, stream>>>(
            statebf, wt + 0 * WSZ, nullptr, nullptr, qb, M, 512, 512);
        gemm_mfma_k<false, false, false, true><<<dim3(8, 64), 256, 0, stream>>>(
            kvbf, wt + 1 * WSZ, nullptr, nullptr, kb, M, 512, 512);
        gemm_mfma_k<false, false, false, true><<<dim3(8, 64), 256, 0, stream>>>(
            kvbf, wt + 2 * WSZ, nullptr, nullptr, vb, M, 512, 512);
        attn_k<<<dim3(SS / 16, HH, BB), 256, 0, stream>>>(qb, kb, vb, ob, pad);
        gemm_mfma_k<false, true, false, false><<<dim3(8, 64), 256, 0, stream>>>(
            ob, wt + 3 * WSZ, nullptr, statef, t0, M, 512, 512);
        ln_k<<<M, 256, 0, stream>>>(t0, g, bb, statef, statebf);
    };
    auto do_ffn = [&](float* statef, ushort* statebf,
                      const float* w1, const float* b1, const float* w2, const float* b2,
                      const float* g, const float* bb) {
        tcast_k<<<dim3(32, 8, 1), 256, 0, stream>>>(w1, w1, w1, w1, wt, 512, DFFv);
        gemm_mfma_k<true, false, true, true><<<dim3(32, 64), 256, 0, stream>>>(
            statebf, wt, b1, nullptr, hbf, M, DFFv, 512);
        tcast_k<<<dim3(8, 32, 1), 256, 0, stream>>>(w2, w2, w2, w2, wt, DFFv, 512);
        gemm_mfma_k<true, true, false, false><<<dim3(8, 64), 256, 0, stream>>>(
            hbf, wt, b2, statef, t0, M, 512, DFFv);
        ln_k<<<M, 256, 0, stream>>>(t0, g, bb, statef, statebf);
    };

    for (int l = 0; l < LL; ++l) {
        do_mha(x, xbf, xbf,
               e_wq + (size_t)l * DD * 512, e_wk + (size_t)l * DD * 512,
               e_wv + (size_t)l * DD * 512, e_wo + (size_t)l * 512 * DD,
               e_g1 + l * DD, e_b1 + l * DD, enc_pad);
        do_ffn(x, xbf, e_w1 + (size_t)l * DD * DFFv, e_bb1 + l * DFFv,
               e_w2 + (size_t)l * DFFv * DD, e_bb2 + l * DD,
               e_g2 + l * DD, e_b2 + l * DD);
    }
    for (int l = 0; l < LL; ++l) {
        do_mha(y, ybf, ybf,
               d_swq + (size_t)l * DD * 512, d_swk + (size_t)l * DD * 512,
               d_swv + (size_t)l * DD * 512, d_swo + (size_t)l * 512 * DD,
               d_g1 + l * DD, d_b1 + l * DD, dec_pad);
        do_mha(y, ybf, xbf,
               d_cwq + (size_t)l * DD * 512, d_cwk + (size_t)l * DD * 512,
               d_cwv + (size_t)l * DD * 512, d_cwo + (size_t)l * 512 * DD,
               d_g2 + l * DD, d_b2 + l * DD, enc_pad);
        do_ffn(y, ybf, d_w1 + (size_t)l * DD * DFFv, d_bb1 + l * DFFv,
               d_w2 + (size_t)l * DFFv * DD, d_bb2 + l * DD,
               d_g3 + l * DD, d_b3 + l * DD);
    }

    copy_k<<<NTOK / 4 / 256, 256, 0, stream>>>(y, (float*)d_out);
}

// Round 4
// 862.525 us; speedup vs baseline: 6.3150x; 1.4903x over previous
//
#include <hip/hip_runtime.h>
#include <hip/hip_bf16.h>

// Problem constants
#define BB 8
#define SS 512
#define DD 512
#define HH 8
#define DQKv 64
#define DFFv 2048
#define LL 2

typedef __attribute__((ext_vector_type(8))) __bf16 bf16x8;
typedef __attribute__((ext_vector_type(4))) float f32x4;

// fp32 -> bf16 (RNE), bf16 -> fp32 helpers on raw ushort bits
static __device__ __forceinline__ ushort f2b(float x) {
    unsigned int u = __float_as_uint(x);
    unsigned int r = (u + 0x7FFFu + ((u >> 16) & 1u)) >> 16;
    return (ushort)r;
}
static __device__ __forceinline__ float b2f(ushort u) {
    return __uint_as_float(((unsigned int)u) << 16);
}

// ---------------------------------------------------------------------------
// Sinusoidal positional encoding
// ---------------------------------------------------------------------------
__global__ __launch_bounds__(256) void pe_k(float* __restrict__ pe) {
    int idx = blockIdx.x * 256 + threadIdx.x;
    int s = idx >> 8;
    int i = idx & 255;
    float div = __expf((float)(2 * i) * (-9.210340371976184f / 512.0f));
    float arg = (float)s * div;
    pe[s * DD + 2 * i]     = sinf(arg);
    pe[s * DD + 2 * i + 1] = cosf(arg);
}

// x = in + pe (broadcast over batch); writes fp32 + bf16 copies
__global__ __launch_bounds__(256) void add_pe_k(const float* __restrict__ in,
                                                const float* __restrict__ pe,
                                                float* __restrict__ outf,
                                                ushort* __restrict__ outb) {
    int i = blockIdx.x * 256 + threadIdx.x;        // over B*S*D/4
    int rem = i & (SS * DD / 4 - 1);
    float4 a = ((const float4*)in)[i];
    float4 p = ((const float4*)pe)[rem];
    a.x += p.x; a.y += p.y; a.z += p.z; a.w += p.w;
    ((float4*)outf)[i] = a;
    ushort4 ub;
    ub.x = f2b(a.x); ub.y = f2b(a.y); ub.z = f2b(a.z); ub.w = f2b(a.w);
    ((ushort4*)outb)[i] = ub;
}

__global__ __launch_bounds__(256) void copy_k(const float* __restrict__ in,
                                              float* __restrict__ out) {
    int i = blockIdx.x * 256 + threadIdx.x;
    ((float4*)out)[i] = ((const float4*)in)[i];
}

// ---------------------------------------------------------------------------
// Weight transpose + cast: src (K x N fp32, pick by blockIdx.z) -> dst (N x K bf16)
// ---------------------------------------------------------------------------
__global__ __launch_bounds__(256) void tcast_k(const float* __restrict__ s0,
                                               const float* __restrict__ s1,
                                               const float* __restrict__ s2,
                                               const float* __restrict__ s3,
                                               ushort* __restrict__ dst,
                                               int K, int N) {
    __shared__ ushort st[64][72];
    const float* src = (blockIdx.z == 0) ? s0 : (blockIdx.z == 1) ? s1
                     : (blockIdx.z == 2) ? s2 : s3;
    ushort* d = dst + (size_t)blockIdx.z * K * N;
    const int k0 = blockIdx.y * 64, n0 = blockIdx.x * 64;
    const int t = threadIdx.x;
    const int r = t >> 2, c4 = (t & 3) * 16;
#pragma unroll
    for (int i = 0; i < 16; i += 4) {
        float4 v = *(const float4*)&src[(size_t)(k0 + r) * N + n0 + c4 + i];
        st[c4 + i + 0][r] = f2b(v.x);
        st[c4 + i + 1][r] = f2b(v.y);
        st[c4 + i + 2][r] = f2b(v.z);
        st[c4 + i + 3][r] = f2b(v.w);
    }
    __syncthreads();
    const int n = t >> 2, seg = (t & 3) * 16;
    *(uint4*)&d[(size_t)(n0 + n) * K + k0 + seg]     = *(const uint4*)&st[n][seg];
    *(uint4*)&d[(size_t)(n0 + n) * K + k0 + seg + 8] = *(const uint4*)&st[n][seg + 8];
}

// ---------------------------------------------------------------------------
// bf16 MFMA GEMM: C(M,N) = A(M,K) @ Bt(N,K)^T  [+bias] [+res] [relu]
// 64x64 tile, BK=64, 256 threads (4 waves), each wave 32x32 via 2x2 16x16x32.
// ---------------------------------------------------------------------------
template <bool BIAS, bool RES, bool RELU, bool OUTBF>
__global__ __launch_bounds__(256) void gemm_mfma_k(const ushort* __restrict__ A,
                                                   const ushort* __restrict__ Bt,
                                                   const float* __restrict__ bias,
                                                   const float* __restrict__ res,
                                                   void* __restrict__ Cout,
                                                   int M, int N, int K) {
    __shared__ ushort As[64][72];
    __shared__ ushort Bs[64][72];
    const int tid = threadIdx.x;
    const int bx = blockIdx.x, by = blockIdx.y;
    const int lane = tid & 63, w = tid >> 6;
    const int rw = (w >> 1) * 32, cw = (w & 1) * 32;

    const int srow = tid >> 2;          // 0..63
    const int sseg = (tid & 3) * 16;    // ushort offset within row
    const ushort* Ap = A + (size_t)(by * 64 + srow) * K + sseg;
    const ushort* Bp = Bt + (size_t)(bx * 64 + srow) * K + sseg;

    f32x4 acc[2][2] = {};

    const int lrow = lane & 15;
    const int lk = (lane >> 4) * 8;

    for (int k0 = 0; k0 < K; k0 += 64) {
        *(uint4*)&As[srow][sseg]     = *(const uint4*)(Ap + k0);
        *(uint4*)&As[srow][sseg + 8] = *(const uint4*)(Ap + k0 + 8);
        *(uint4*)&Bs[srow][sseg]     = *(const uint4*)(Bp + k0);
        *(uint4*)&Bs[srow][sseg + 8] = *(const uint4*)(Bp + k0 + 8);
        __syncthreads();
#pragma unroll
        for (int ks = 0; ks < 2; ++ks) {
            bf16x8 a0 = *(const bf16x8*)&As[rw + lrow][ks * 32 + lk];
            bf16x8 a1 = *(const bf16x8*)&As[rw + 16 + lrow][ks * 32 + lk];
            bf16x8 b0 = *(const bf16x8*)&Bs[cw + lrow][ks * 32 + lk];
            bf16x8 b1 = *(const bf16x8*)&Bs[cw + 16 + lrow][ks * 32 + lk];
            acc[0][0] = __builtin_amdgcn_mfma_f32_16x16x32_bf16(a0, b0, acc[0][0], 0, 0, 0);
            acc[0][1] = __builtin_amdgcn_mfma_f32_16x16x32_bf16(a0, b1, acc[0][1], 0, 0, 0);
            acc[1][0] = __builtin_amdgcn_mfma_f32_16x16x32_bf16(a1, b0, acc[1][0], 0, 0, 0);
            acc[1][1] = __builtin_amdgcn_mfma_f32_16x16x32_bf16(a1, b1, acc[1][1], 0, 0, 0);
        }
        __syncthreads();
    }

    // Epilogue. C/D frag: col = lane&15, row = (lane>>4)*4 + j  [verified m89]
    const int crow0 = by * 64 + rw + (lane >> 4) * 4;
    const int ccol0 = bx * 64 + cw + lrow;
#pragma unroll
    for (int m = 0; m < 2; ++m) {
#pragma unroll
        for (int n = 0; n < 2; ++n) {
            const int col = ccol0 + n * 16;
            const float bv = BIAS ? bias[col] : 0.f;
#pragma unroll
            for (int j = 0; j < 4; ++j) {
                const int row = crow0 + m * 16 + j;
                float v = acc[m][n][j] + bv;
                if (RES) v += res[(size_t)row * N + col];
                if (RELU) v = fmaxf(v, 0.f);
                if (OUTBF) ((ushort*)Cout)[(size_t)row * N + col] = f2b(v);
                else       ((float*)Cout)[(size_t)row * N + col] = v;
            }
        }
    }
}

// ---------------------------------------------------------------------------
// MFMA flash attention: one block per (b, h, 64 q-rows), 4 waves, wave owns
// 16 q-rows. Per 64-key tile: QK^T (8 mfma) -> online softmax (register
// local + 16-lane shfl) -> P bf16 to wave-local LDS -> PV (8 mfma).
// Scale applied to S after MFMA (x0.125, exact). Window/klim semantics and
// all-masked-uniform fallback identical to verified R3 kernel.
// ---------------------------------------------------------------------------
__global__ __launch_bounds__(256) void attn_k(const ushort* __restrict__ Q,
                                              const ushort* __restrict__ Kb,
                                              const ushort* __restrict__ Vb,
                                              ushort* __restrict__ O,
                                              const int* __restrict__ pad) {
    __shared__ ushort sQ[64][72];
    __shared__ ushort sK[64][72];
    __shared__ ushort sVt[64][72];   // V transposed: [d][key]
    __shared__ ushort sP[64][72];    // P: [q][key-local]

    const int tid = threadIdx.x;
    const int b = blockIdx.z, h = blockIdx.y, q0 = blockIdx.x << 6;
    const int klim = SS - pad[b];
    const int lane = tid & 63, w = tid >> 6;
    const int qw0 = w << 4;                // wave's q-row offset within tile
    const int lhi = lane >> 4, llo = lane & 15;

    // ---- stage Q tile (straight bf16 copy) ----
    {
        const int r = tid >> 2, seg = (tid & 3) << 4;
        const ushort* src = &Q[(size_t)(b * SS + q0 + r) * (HH * DQKv) + h * DQKv + seg];
        *(uint4*)&sQ[r][seg]     = *(const uint4*)src;
        *(uint4*)&sQ[r][seg + 8] = *(const uint4*)(src + 8);
    }

    auto window = [&](int i, int& wlo, int& whi) {
        if (h < 6) {
            const int step = 4 << (h >> 1);
            const int s2 = step >> 1;
            const int a1 = (i < s2) ? i : s2;
            const int a2 = ((SS - 1 - i) < s2) ? (SS - 1 - i) : s2;
            const int left = (i < SS / 2) ? a1 : (step - a2);
            wlo = i - left;
            whi = wlo + step;
        } else {
            wlo = 0;
            whi = SS - 1;
        }
    };

    // per-register-row windows: q = q0 + qw0 + lhi*4 + j
    int lo[4], hi[4];
#pragma unroll
    for (int j = 0; j < 4; ++j) window(q0 + qw0 + lhi * 4 + j, lo[j], hi[j]);

    int kt0 = 0, kt1 = SS;
    if (h < 6) {
        int lo0, hi0, lo63, hi63;
        window(q0, lo0, hi0);
        window(q0 + 63, lo63, hi63);
        if (lo63 >= klim) {
            kt0 = 0; kt1 = SS;          // all-masked row possible -> full range
        } else {
            kt0 = (lo0 >> 6) << 6;
            kt1 = ((hi63 >> 6) + 1) << 6;
            if (kt1 > SS) kt1 = SS;
        }
    }

    float mr[4] = {-1e30f, -1e30f, -1e30f, -1e30f};
    float lr[4] = {0.f, 0.f, 0.f, 0.f};
    f32x4 oacc[4] = {};   // [d-tile n], vector index = j

    for (int kt = kt0; kt < kt1; kt += 64) {
        __syncthreads();   // prev-iter reads of sK/sVt done before restage
        {
            const int r = tid >> 2, seg = (tid & 3) << 4;
            const ushort* ksrc = &Kb[(size_t)(b * SS + kt + r) * (HH * DQKv) + h * DQKv + seg];
            *(uint4*)&sK[r][seg]     = *(const uint4*)ksrc;
            *(uint4*)&sK[r][seg + 8] = *(const uint4*)(ksrc + 8);
            const ushort* vsrc = &Vb[(size_t)(b * SS + kt + r) * (HH * DQKv) + h * DQKv + seg];
            uint4 u0 = *(const uint4*)vsrc;
            uint4 u1 = *(const uint4*)(vsrc + 8);
            const ushort* v0 = (const ushort*)&u0;
            const ushort* v1 = (const ushort*)&u1;
#pragma unroll
            for (int i = 0; i < 8; ++i) sVt[seg + i][r] = v0[i];
#pragma unroll
            for (int i = 0; i < 8; ++i) sVt[seg + 8 + i][r] = v1[i];
        }
        __syncthreads();

        // ---- QK^T ----
        f32x4 sacc[4] = {};
#pragma unroll
        for (int ks = 0; ks < 2; ++ks) {
            bf16x8 aq = *(const bf16x8*)&sQ[qw0 + llo][ks * 32 + lhi * 8];
#pragma unroll
            for (int n = 0; n < 4; ++n) {
                bf16x8 bk = *(const bf16x8*)&sK[n * 16 + llo][ks * 32 + lhi * 8];
                sacc[n] = __builtin_amdgcn_mfma_f32_16x16x32_bf16(aq, bk, sacc[n], 0, 0, 0);
            }
        }

        // ---- mask + scale + online softmax (per register row j) ----
#pragma unroll
        for (int j = 0; j < 4; ++j) {
            float s[4];
#pragma unroll
            for (int n = 0; n < 4; ++n) {
                const int kidx = kt + n * 16 + llo;
                const bool ok = (kidx < klim) && (kidx >= lo[j]) && (kidx <= hi[j]);
                s[n] = ok ? (sacc[n][j] * 0.125f) : -1e9f;
            }
            float tm = fmaxf(fmaxf(s[0], s[1]), fmaxf(s[2], s[3]));
#pragma unroll
            for (int off = 8; off; off >>= 1) tm = fmaxf(tm, __shfl_xor(tm, off));
            const float mn = fmaxf(mr[j], tm);
            const float alpha = __expf(mr[j] - mn);
            mr[j] = mn;
            float ps = 0.f;
            const int prow = qw0 + lhi * 4 + j;
#pragma unroll
            for (int n = 0; n < 4; ++n) {
                const ushort pb = f2b(__expf(s[n] - mn));
                sP[prow][n * 16 + llo] = pb;
                ps += b2f(pb);          // l consistent with bf16-rounded P
            }
#pragma unroll
            for (int off = 8; off; off >>= 1) ps += __shfl_xor(ps, off);
            lr[j] = lr[j] * alpha + ps;
            oacc[0][j] *= alpha; oacc[1][j] *= alpha;
            oacc[2][j] *= alpha; oacc[3][j] *= alpha;
        }

        // ---- PV (sP rows are wave-local; program order suffices) ----
#pragma unroll
        for (int ks = 0; ks < 2; ++ks) {
            bf16x8 ap = *(const bf16x8*)&sP[qw0 + llo][ks * 32 + lhi * 8];
#pragma unroll
            for (int n = 0; n < 4; ++n) {
                bf16x8 bv = *(const bf16x8*)&sVt[n * 16 + llo][ks * 32 + lhi * 8];
                oacc[n] = __builtin_amdgcn_mfma_f32_16x16x32_bf16(ap, bv, oacc[n], 0, 0, 0);
            }
        }
    }

    // ---- epilogue ----
#pragma unroll
    for (int j = 0; j < 4; ++j) {
        const float inv = 1.f / lr[j];
        const int q = q0 + qw0 + lhi * 4 + j;
#pragma unroll
        for (int n = 0; n < 4; ++n) {
            O[(size_t)(b * SS + q) * (HH * DQKv) + h * DQKv + n * 16 + llo] =
                f2b(oacc[n][j] * inv);
        }
    }
}

// ---------------------------------------------------------------------------
// LayerNorm over rows of 512; writes fp32 state + bf16 state copy
// ---------------------------------------------------------------------------
__global__ __launch_bounds__(256) void ln_k(const float* __restrict__ in,
                                            const float* __restrict__ g,
                                            const float* __restrict__ bvec,
                                            float* __restrict__ outf,
                                            ushort* __restrict__ outb) {
    const int row = blockIdx.x;
    const int tid = threadIdx.x;
    const float2 xv = *(const float2*)&in[(size_t)row * DD + tid * 2];

    __shared__ float red[4];
    __shared__ float red2[4];
    const int wid = tid >> 6, lane = tid & 63;

    float s = xv.x + xv.y;
#pragma unroll
    for (int off = 32; off; off >>= 1) s += __shfl_xor(s, off);
    if (lane == 0) red[wid] = s;
    __syncthreads();
    const float mu = (red[0] + red[1] + red[2] + red[3]) * (1.f / 512.f);

    const float dx = xv.x - mu, dy = xv.y - mu;
    float q = dx * dx + dy * dy;
#pragma unroll
    for (int off = 32; off; off >>= 1) q += __shfl_xor(q, off);
    if (lane == 0) red2[wid] = q;
    __syncthreads();
    const float var = (red2[0] + red2[1] + red2[2] + red2[3]) * (1.f / 512.f);
    const float rs = rsqrtf(var + 1e-6f);

    float2 o;
    o.x = dx * rs * g[tid * 2] + bvec[tid * 2];
    o.y = dy * rs * g[tid * 2 + 1] + bvec[tid * 2 + 1];
    *(float2*)&outf[(size_t)row * DD + tid * 2] = o;
    ushort2 ub; ub.x = f2b(o.x); ub.y = f2b(o.y);
    *(ushort2*)&outb[(size_t)row * DD + tid * 2] = ub;
}

// ---------------------------------------------------------------------------
// Host orchestration
// ---------------------------------------------------------------------------
extern "C" void kernel_launch(void* const* d_in, const int* in_sizes, int n_in,
                              void* d_out, int out_size, void* d_ws, size_t ws_size,
                              hipStream_t stream) {
    const float* src_seq = (const float*)d_in[0];
    const float* trg_seq = (const float*)d_in[1];
    const int* enc_pad = (const int*)d_in[2];
    const int* dec_pad = (const int*)d_in[3];
    const float* e_wq = (const float*)d_in[4];
    const float* e_wk = (const float*)d_in[5];
    const float* e_wv = (const float*)d_in[6];
    const float* e_wo = (const float*)d_in[7];
    const float* e_g1 = (const float*)d_in[8];
    const float* e_b1 = (const float*)d_in[9];
    const float* e_w1 = (const float*)d_in[10];
    const float* e_bb1 = (const float*)d_in[11];
    const float* e_w2 = (const float*)d_in[12];
    const float* e_bb2 = (const float*)d_in[13];
    const float* e_g2 = (const float*)d_in[14];
    const float* e_b2 = (const float*)d_in[15];
    const float* d_swq = (const float*)d_in[16];
    const float* d_swk = (const float*)d_in[17];
    const float* d_swv = (const float*)d_in[18];
    const float* d_swo = (const float*)d_in[19];
    const float* d_g1 = (const float*)d_in[20];
    const float* d_b1 = (const float*)d_in[21];
    const float* d_cwq = (const float*)d_in[22];
    const float* d_cwk = (const float*)d_in[23];
    const float* d_cwv = (const float*)d_in[24];
    const float* d_cwo = (const float*)d_in[25];
    const float* d_g2 = (const float*)d_in[26];
    const float* d_b2 = (const float*)d_in[27];
    const float* d_w1 = (const float*)d_in[28];
    const float* d_bb1 = (const float*)d_in[29];
    const float* d_w2 = (const float*)d_in[30];
    const float* d_bb2 = (const float*)d_in[31];
    const float* d_g3 = (const float*)d_in[32];
    const float* d_b3 = (const float*)d_in[33];
    (void)in_sizes; (void)n_in; (void)out_size; (void)ws_size;

    const int M = BB * SS;          // 4096
    const int NSD = SS * DD;        // 262144
    const int NTOK = BB * SS * DD;  // 2097152
    const size_t WSZ = (size_t)DD * 512;  // 262144 (one 512x512 weight)

    float* ws = (float*)d_ws;
    float* pe = ws;
    float* x  = pe + NSD;
    float* y  = x + NTOK;
    float* t0 = y + NTOK;
    ushort* xbf = (ushort*)(t0 + NTOK);
    ushort* ybf = xbf + NTOK;
    ushort* qb  = ybf + NTOK;
    ushort* kb  = qb + NTOK;
    ushort* vb  = kb + NTOK;
    ushort* ob  = vb + NTOK;
    ushort* hbf = qb;               // FFN hidden (4096x2048 bf16) aliases qb..ob
    ushort* wt  = ob + NTOK;        // 1M bf16 transposed-weight scratch (2 MB)

    pe_k<<<SS, 256, 0, stream>>>(pe);
    add_pe_k<<<NTOK / 4 / 256, 256, 0, stream>>>(src_seq, pe, x, xbf);
    add_pe_k<<<NTOK / 4 / 256, 256, 0, stream>>>(trg_seq, pe, y, ybf);

    auto do_mha = [&](float* statef, ushort* statebf, const ushort* kvbf,
                      const float* wq, const float* wk, const float* wv, const float* wo,
                      const float* g, const float* bb, const int* pad) {
        tcast_k<<<dim3(8, 8, 4), 256, 0, stream>>>(wq, wk, wv, wo, wt, 512, 512);
        gemm_mfma_k<false, false, false, true><<<dim3(8, 64), 256, 0, stream>>>(
            statebf, wt + 0 * WSZ, nullptr, nullptr, qb, M, 512, 512);
        gemm_mfma_k<false, false, false, true><<<dim3(8, 64), 256, 0, stream>>>(
            kvbf, wt + 1 * WSZ, nullptr, nullptr, kb, M, 512, 512);
        gemm_mfma_k<false, false, false, true><<<dim3(8, 64), 256, 0, stream>>>(
            kvbf, wt + 2 * WSZ, nullptr, nullptr, vb, M, 512, 512);
        attn_k<<<dim3(SS / 64, HH, BB), 256, 0, stream>>>(qb, kb, vb, ob, pad);
        gemm_mfma_k<false, true, false, false><<<dim3(8, 64), 256, 0, stream>>>(
            ob, wt + 3 * WSZ, nullptr, statef, t0, M, 512, 512);
        ln_k<<<M, 256, 0, stream>>>(t0, g, bb, statef, statebf);
    };
    auto do_ffn = [&](float* statef, ushort* statebf,
                      const float* w1, const float* b1, const float* w2, const float* b2,
                      const float* g, const float* bb) {
        tcast_k<<<dim3(32, 8, 1), 256, 0, stream>>>(w1, w1, w1, w1, wt, 512, DFFv);
        gemm_mfma_k<true, false, true, true><<<dim3(32, 64), 256, 0, stream>>>(
            statebf, wt, b1, nullptr, hbf, M, DFFv, 512);
        tcast_k<<<dim3(8, 32, 1), 256, 0, stream>>>(w2, w2, w2, w2, wt, DFFv, 512);
        gemm_mfma_k<true, true, false, false><<<dim3(8, 64), 256, 0, stream>>>(
            hbf, wt, b2, statef, t0, M, 512, DFFv);
        ln_k<<<M, 256, 0, stream>>>(t0, g, bb, statef, statebf);
    };

    for (int l = 0; l < LL; ++l) {
        do_mha(x, xbf, xbf,
               e_wq + (size_t)l * DD * 512, e_wk + (size_t)l * DD * 512,
               e_wv + (size_t)l * DD * 512, e_wo + (size_t)l * 512 * DD,
               e_g1 + l * DD, e_b1 + l * DD, enc_pad);
        do_ffn(x, xbf, e_w1 + (size_t)l * DD * DFFv, e_bb1 + l * DFFv,
               e_w2 + (size_t)l * DFFv * DD, e_bb2 + l * DD,
               e_g2 + l * DD, e_b2 + l * DD);
    }
    for (int l = 0; l < LL; ++l) {
        do_mha(y, ybf, ybf,
               d_swq + (size_t)l * DD * 512, d_swk + (size_t)l * DD * 512,
               d_swv + (size_t)l * DD * 512, d_swo + (size_t)l * 512 * DD,
               d_g1 + l * DD, d_b1 + l * DD, dec_pad);
        do_mha(y, ybf, xbf,
               d_cwq + (size_t)l * DD * 512, d_cwk + (size_t)l * DD * 512,
               d_cwv + (size_t)l * DD * 512, d_cwo + (size_t)l * 512 * DD,
               d_g2 + l * DD, d_b2 + l * DD, enc_pad);
        do_ffn(y, ybf, d_w1 + (size_t)l * DD * DFFv, d_bb1 + l * DFFv,
               d_w2 + (size_t)l * DFFv * DD, d_bb2 + l * DD,
               d_g3 + l * DD, d_b3 + l * DD);
    }

    copy_k<<<NTOK / 4 / 256, 256, 0, stream>>>(y, (float*)d_out);
}

// Round 5
// 720.102 us; speedup vs baseline: 7.5640x; 1.1978x over previous
//
#include <hip/hip_runtime.h>
#include <hip/hip_bf16.h>

// Problem constants
#define BB 8
#define SS 512
#define DD 512
#define HH 8
#define DQKv 64
#define DFFv 2048
#define LL 2

typedef __attribute__((ext_vector_type(8))) __bf16 bf16x8;
typedef __attribute__((ext_vector_type(4))) float f32x4;

// fp32 -> bf16 (RNE), bf16 -> fp32 helpers on raw ushort bits
static __device__ __forceinline__ ushort f2b(float x) {
    unsigned int u = __float_as_uint(x);
    unsigned int r = (u + 0x7FFFu + ((u >> 16) & 1u)) >> 16;
    return (ushort)r;
}
static __device__ __forceinline__ float b2f(ushort u) {
    return __uint_as_float(((unsigned int)u) << 16);
}

typedef __attribute__((address_space(1))) const unsigned int gas_u32;
typedef __attribute__((address_space(3))) unsigned int las_u32;
static __device__ __forceinline__ void gload16(const void* g, void* l) {
    __builtin_amdgcn_global_load_lds((gas_u32*)g, (las_u32*)l, 16, 0, 0);
}

// ---------------------------------------------------------------------------
// Sinusoidal positional encoding
// ---------------------------------------------------------------------------
__global__ __launch_bounds__(256) void pe_k(float* __restrict__ pe) {
    int idx = blockIdx.x * 256 + threadIdx.x;
    int s = idx >> 8;
    int i = idx & 255;
    float div = __expf((float)(2 * i) * (-9.210340371976184f / 512.0f));
    float arg = (float)s * div;
    pe[s * DD + 2 * i]     = sinf(arg);
    pe[s * DD + 2 * i + 1] = cosf(arg);
}

// x = in + pe (broadcast over batch); writes fp32 + bf16 copies
__global__ __launch_bounds__(256) void add_pe_k(const float* __restrict__ in,
                                                const float* __restrict__ pe,
                                                float* __restrict__ outf,
                                                ushort* __restrict__ outb) {
    int i = blockIdx.x * 256 + threadIdx.x;        // over B*S*D/4
    int rem = i & (SS * DD / 4 - 1);
    float4 a = ((const float4*)in)[i];
    float4 p = ((const float4*)pe)[rem];
    a.x += p.x; a.y += p.y; a.z += p.z; a.w += p.w;
    ((float4*)outf)[i] = a;
    ushort4 ub;
    ub.x = f2b(a.x); ub.y = f2b(a.y); ub.z = f2b(a.z); ub.w = f2b(a.w);
    ((ushort4*)outb)[i] = ub;
}

__global__ __launch_bounds__(256) void copy_k(const float* __restrict__ in,
                                              float* __restrict__ out) {
    int i = blockIdx.x * 256 + threadIdx.x;
    ((float4*)out)[i] = ((const float4*)in)[i];
}

// ---------------------------------------------------------------------------
// Weight transpose + cast: src (K x N fp32, pick by blockIdx.z) -> dst (N x K bf16)
// ---------------------------------------------------------------------------
__global__ __launch_bounds__(256) void tcast_k(const float* __restrict__ s0,
                                               const float* __restrict__ s1,
                                               const float* __restrict__ s2,
                                               const float* __restrict__ s3,
                                               ushort* __restrict__ dst,
                                               int K, int N) {
    __shared__ ushort st[64][72];
    const float* src = (blockIdx.z == 0) ? s0 : (blockIdx.z == 1) ? s1
                     : (blockIdx.z == 2) ? s2 : s3;
    ushort* d = dst + (size_t)blockIdx.z * K * N;
    const int k0 = blockIdx.y * 64, n0 = blockIdx.x * 64;
    const int t = threadIdx.x;
    const int r = t >> 2, c4 = (t & 3) * 16;
#pragma unroll
    for (int i = 0; i < 16; i += 4) {
        float4 v = *(const float4*)&src[(size_t)(k0 + r) * N + n0 + c4 + i];
        st[c4 + i + 0][r] = f2b(v.x);
        st[c4 + i + 1][r] = f2b(v.y);
        st[c4 + i + 2][r] = f2b(v.z);
        st[c4 + i + 3][r] = f2b(v.w);
    }
    __syncthreads();
    const int n = t >> 2, seg = (t & 3) * 16;
    *(uint4*)&d[(size_t)(n0 + n) * K + k0 + seg]     = *(const uint4*)&st[n][seg];
    *(uint4*)&d[(size_t)(n0 + n) * K + k0 + seg + 8] = *(const uint4*)&st[n][seg + 8];
}

// ---------------------------------------------------------------------------
// bf16 MFMA GEMM, m97-style: C(M,N) = A(M,K) @ Bt(N,K)^T [+bias][+res][relu]
// BM=128, BN=64, BK=64. 256 threads = 4 waves (2x2), wave does 64x32 via
// 4x2 16x16x32 frags. Staging via global_load_lds width 16 (linear LDS).
// 1D grid = (M/128)*(N/64) with bijective XCD swizzle (grid % 8 == 0).
// ---------------------------------------------------------------------------
template <bool BIAS, bool RES, bool RELU, bool OUTBF>
__global__ __launch_bounds__(256) void gemm2_k(const ushort* __restrict__ A,
                                               const ushort* __restrict__ Bt,
                                               const float* __restrict__ bias,
                                               const float* __restrict__ res,
                                               void* __restrict__ Cout,
                                               int M, int N, int K, int nbx) {
    __shared__ ushort sA[128 * 64];
    __shared__ ushort sB[64 * 64];

    const int tid = threadIdx.x;
    const int nwg = gridDim.x;
    const int wg = blockIdx.x;
    const int swz = (wg & 7) * (nwg >> 3) + (wg >> 3);   // XCD-contiguous chunks
    const int bx = swz % nbx, by = swz / nbx;

    const int lane = tid & 63, w = tid >> 6;
    const int wm = w >> 1, wn = w & 1;
    const int llo = lane & 15, lhi = lane >> 4;

    const int srow = tid >> 3;           // 0..31
    const int scol = (tid & 7) * 8;      // element offset in row (8 elems=16B)
    const ushort* Ab = A + (size_t)(by * 128 + srow) * K + scol;
    const ushort* Bb = Bt + (size_t)(bx * 64 + srow) * K + scol;
    char* sAd = (char*)sA + srow * 128 + (tid & 7) * 16;
    char* sBd = (char*)sB + srow * 128 + (tid & 7) * 16;

    f32x4 acc[4][2] = {};

    for (int k0 = 0; k0 < K; k0 += 64) {
#pragma unroll
        for (int i = 0; i < 4; ++i)
            gload16(Ab + (size_t)i * 32 * K + k0, sAd + i * 32 * 128);
#pragma unroll
        for (int i = 0; i < 2; ++i)
            gload16(Bb + (size_t)i * 32 * K + k0, sBd + i * 32 * 128);
        __syncthreads();   // drains vmcnt before barrier

#pragma unroll
        for (int ks = 0; ks < 2; ++ks) {
            bf16x8 af[4];
#pragma unroll
            for (int fa = 0; fa < 4; ++fa)
                af[fa] = *(const bf16x8*)&sA[(wm * 64 + fa * 16 + llo) * 64 + ks * 32 + lhi * 8];
            bf16x8 bfrag[2];
#pragma unroll
            for (int fb = 0; fb < 2; ++fb)
                bfrag[fb] = *(const bf16x8*)&sB[(wn * 32 + fb * 16 + llo) * 64 + ks * 32 + lhi * 8];
#pragma unroll
            for (int fa = 0; fa < 4; ++fa)
#pragma unroll
                for (int fb = 0; fb < 2; ++fb)
                    acc[fa][fb] = __builtin_amdgcn_mfma_f32_16x16x32_bf16(
                        af[fa], bfrag[fb], acc[fa][fb], 0, 0, 0);
        }
        __syncthreads();   // all reads done before next stage
    }

    // Epilogue. C/D frag: col = lane&15, row = (lane>>4)*4 + j
#pragma unroll
    for (int fa = 0; fa < 4; ++fa) {
#pragma unroll
        for (int fb = 0; fb < 2; ++fb) {
            const int col = bx * 64 + wn * 32 + fb * 16 + llo;
            const float bv = BIAS ? bias[col] : 0.f;
#pragma unroll
            for (int j = 0; j < 4; ++j) {
                const int row = by * 128 + wm * 64 + fa * 16 + lhi * 4 + j;
                float v = acc[fa][fb][j] + bv;
                if (RES) v += res[(size_t)row * N + col];
                if (RELU) v = fmaxf(v, 0.f);
                if (OUTBF) ((ushort*)Cout)[(size_t)row * N + col] = f2b(v);
                else       ((float*)Cout)[(size_t)row * N + col] = v;
            }
        }
    }
}

// ---------------------------------------------------------------------------
// MFMA flash attention on packed QKV [M][1536] (Q cols 0-511, K 512-1023,
// V 1024-1535; head h at h*64 within segment). One block per (b,h,64 q-rows),
// 4 waves, wave owns 16 q-rows. Semantics identical to R4 (window masks,
// klim, all-masked-uniform fallback).
// ---------------------------------------------------------------------------
__global__ __launch_bounds__(256) void attn_k(const ushort* __restrict__ QKV,
                                              ushort* __restrict__ O,
                                              const int* __restrict__ pad) {
    __shared__ ushort sQ[64][72];
    __shared__ ushort sK[64][72];
    __shared__ ushort sVt[64][72];   // V transposed: [d][key]
    __shared__ ushort sP[64][72];    // P: [q][key-local]

    const int tid = threadIdx.x;
    const int b = blockIdx.z, h = blockIdx.y, q0 = blockIdx.x << 6;
    const int klim = SS - pad[b];
    const int lane = tid & 63, w = tid >> 6;
    const int qw0 = w << 4;
    const int lhi = lane >> 4, llo = lane & 15;
    const int ST = 3 * DD;           // 1536 row stride

    // ---- stage Q tile ----
    {
        const int r = tid >> 2, seg = (tid & 3) << 4;
        const ushort* src = &QKV[(size_t)(b * SS + q0 + r) * ST + h * DQKv + seg];
        *(uint4*)&sQ[r][seg]     = *(const uint4*)src;
        *(uint4*)&sQ[r][seg + 8] = *(const uint4*)(src + 8);
    }

    auto window = [&](int i, int& wlo, int& whi) {
        if (h < 6) {
            const int step = 4 << (h >> 1);
            const int s2 = step >> 1;
            const int a1 = (i < s2) ? i : s2;
            const int a2 = ((SS - 1 - i) < s2) ? (SS - 1 - i) : s2;
            const int left = (i < SS / 2) ? a1 : (step - a2);
            wlo = i - left;
            whi = wlo + step;
        } else {
            wlo = 0;
            whi = SS - 1;
        }
    };

    int lo[4], hi[4];
#pragma unroll
    for (int j = 0; j < 4; ++j) window(q0 + qw0 + lhi * 4 + j, lo[j], hi[j]);

    int kt0 = 0, kt1 = SS;
    if (h < 6) {
        int lo0, hi0, lo63, hi63;
        window(q0, lo0, hi0);
        window(q0 + 63, lo63, hi63);
        if (lo63 >= klim) {
            kt0 = 0; kt1 = SS;
        } else {
            kt0 = (lo0 >> 6) << 6;
            kt1 = ((hi63 >> 6) + 1) << 6;
            if (kt1 > SS) kt1 = SS;
        }
    }

    float mr[4] = {-1e30f, -1e30f, -1e30f, -1e30f};
    float lr[4] = {0.f, 0.f, 0.f, 0.f};
    f32x4 oacc[4] = {};

    for (int kt = kt0; kt < kt1; kt += 64) {
        __syncthreads();
        {
            const int r = tid >> 2, seg = (tid & 3) << 4;
            const ushort* ksrc = &QKV[(size_t)(b * SS + kt + r) * ST + DD + h * DQKv + seg];
            *(uint4*)&sK[r][seg]     = *(const uint4*)ksrc;
            *(uint4*)&sK[r][seg + 8] = *(const uint4*)(ksrc + 8);
            const ushort* vsrc = &QKV[(size_t)(b * SS + kt + r) * ST + 2 * DD + h * DQKv + seg];
            uint4 u0 = *(const uint4*)vsrc;
            uint4 u1 = *(const uint4*)(vsrc + 8);
            const ushort* v0 = (const ushort*)&u0;
            const ushort* v1 = (const ushort*)&u1;
#pragma unroll
            for (int i = 0; i < 8; ++i) sVt[seg + i][r] = v0[i];
#pragma unroll
            for (int i = 0; i < 8; ++i) sVt[seg + 8 + i][r] = v1[i];
        }
        __syncthreads();

        // ---- QK^T ----
        f32x4 sacc[4] = {};
#pragma unroll
        for (int ks = 0; ks < 2; ++ks) {
            bf16x8 aq = *(const bf16x8*)&sQ[qw0 + llo][ks * 32 + lhi * 8];
#pragma unroll
            for (int n = 0; n < 4; ++n) {
                bf16x8 bk = *(const bf16x8*)&sK[n * 16 + llo][ks * 32 + lhi * 8];
                sacc[n] = __builtin_amdgcn_mfma_f32_16x16x32_bf16(aq, bk, sacc[n], 0, 0, 0);
            }
        }

        // ---- mask + scale + online softmax ----
#pragma unroll
        for (int j = 0; j < 4; ++j) {
            float s[4];
#pragma unroll
            for (int n = 0; n < 4; ++n) {
                const int kidx = kt + n * 16 + llo;
                const bool ok = (kidx < klim) && (kidx >= lo[j]) && (kidx <= hi[j]);
                s[n] = ok ? (sacc[n][j] * 0.125f) : -1e9f;
            }
            float tm = fmaxf(fmaxf(s[0], s[1]), fmaxf(s[2], s[3]));
#pragma unroll
            for (int off = 8; off; off >>= 1) tm = fmaxf(tm, __shfl_xor(tm, off));
            const float mn = fmaxf(mr[j], tm);
            const float alpha = __expf(mr[j] - mn);
            mr[j] = mn;
            float ps = 0.f;
            const int prow = qw0 + lhi * 4 + j;
#pragma unroll
            for (int n = 0; n < 4; ++n) {
                const ushort pb = f2b(__expf(s[n] - mn));
                sP[prow][n * 16 + llo] = pb;
                ps += b2f(pb);
            }
#pragma unroll
            for (int off = 8; off; off >>= 1) ps += __shfl_xor(ps, off);
            lr[j] = lr[j] * alpha + ps;
            oacc[0][j] *= alpha; oacc[1][j] *= alpha;
            oacc[2][j] *= alpha; oacc[3][j] *= alpha;
        }

        // ---- PV ----
#pragma unroll
        for (int ks = 0; ks < 2; ++ks) {
            bf16x8 ap = *(const bf16x8*)&sP[qw0 + llo][ks * 32 + lhi * 8];
#pragma unroll
            for (int n = 0; n < 4; ++n) {
                bf16x8 bv = *(const bf16x8*)&sVt[n * 16 + llo][ks * 32 + lhi * 8];
                oacc[n] = __builtin_amdgcn_mfma_f32_16x16x32_bf16(ap, bv, oacc[n], 0, 0, 0);
            }
        }
    }

    // ---- epilogue ----
#pragma unroll
    for (int j = 0; j < 4; ++j) {
        const float inv = 1.f / lr[j];
        const int q = q0 + qw0 + lhi * 4 + j;
#pragma unroll
        for (int n = 0; n < 4; ++n) {
            O[(size_t)(b * SS + q) * (HH * DQKv) + h * DQKv + n * 16 + llo] =
                f2b(oacc[n][j] * inv);
        }
    }
}

// ---------------------------------------------------------------------------
// LayerNorm over rows of 512; writes fp32 state + bf16 state copy
// ---------------------------------------------------------------------------
__global__ __launch_bounds__(256) void ln_k(const float* __restrict__ in,
                                            const float* __restrict__ g,
                                            const float* __restrict__ bvec,
                                            float* __restrict__ outf,
                                            ushort* __restrict__ outb) {
    const int row = blockIdx.x;
    const int tid = threadIdx.x;
    const float2 xv = *(const float2*)&in[(size_t)row * DD + tid * 2];

    __shared__ float red[4];
    __shared__ float red2[4];
    const int wid = tid >> 6, lane = tid & 63;

    float s = xv.x + xv.y;
#pragma unroll
    for (int off = 32; off; off >>= 1) s += __shfl_xor(s, off);
    if (lane == 0) red[wid] = s;
    __syncthreads();
    const float mu = (red[0] + red[1] + red[2] + red[3]) * (1.f / 512.f);

    const float dx = xv.x - mu, dy = xv.y - mu;
    float q = dx * dx + dy * dy;
#pragma unroll
    for (int off = 32; off; off >>= 1) q += __shfl_xor(q, off);
    if (lane == 0) red2[wid] = q;
    __syncthreads();
    const float var = (red2[0] + red2[1] + red2[2] + red2[3]) * (1.f / 512.f);
    const float rs = rsqrtf(var + 1e-6f);

    float2 o;
    o.x = dx * rs * g[tid * 2] + bvec[tid * 2];
    o.y = dy * rs * g[tid * 2 + 1] + bvec[tid * 2 + 1];
    *(float2*)&outf[(size_t)row * DD + tid * 2] = o;
    ushort2 ub; ub.x = f2b(o.x); ub.y = f2b(o.y);
    *(ushort2*)&outb[(size_t)row * DD + tid * 2] = ub;
}

// ---------------------------------------------------------------------------
// Host orchestration
// ---------------------------------------------------------------------------
extern "C" void kernel_launch(void* const* d_in, const int* in_sizes, int n_in,
                              void* d_out, int out_size, void* d_ws, size_t ws_size,
                              hipStream_t stream) {
    const float* src_seq = (const float*)d_in[0];
    const float* trg_seq = (const float*)d_in[1];
    const int* enc_pad = (const int*)d_in[2];
    const int* dec_pad = (const int*)d_in[3];
    const float* e_wq = (const float*)d_in[4];
    const float* e_wk = (const float*)d_in[5];
    const float* e_wv = (const float*)d_in[6];
    const float* e_wo = (const float*)d_in[7];
    const float* e_g1 = (const float*)d_in[8];
    const float* e_b1 = (const float*)d_in[9];
    const float* e_w1 = (const float*)d_in[10];
    const float* e_bb1 = (const float*)d_in[11];
    const float* e_w2 = (const float*)d_in[12];
    const float* e_bb2 = (const float*)d_in[13];
    const float* e_g2 = (const float*)d_in[14];
    const float* e_b2 = (const float*)d_in[15];
    const float* d_swq = (const float*)d_in[16];
    const float* d_swk = (const float*)d_in[17];
    const float* d_swv = (const float*)d_in[18];
    const float* d_swo = (const float*)d_in[19];
    const float* d_g1 = (const float*)d_in[20];
    const float* d_b1 = (const float*)d_in[21];
    const float* d_cwq = (const float*)d_in[22];
    const float* d_cwk = (const float*)d_in[23];
    const float* d_cwv = (const float*)d_in[24];
    const float* d_cwo = (const float*)d_in[25];
    const float* d_g2 = (const float*)d_in[26];
    const float* d_b2 = (const float*)d_in[27];
    const float* d_w1 = (const float*)d_in[28];
    const float* d_bb1 = (const float*)d_in[29];
    const float* d_w2 = (const float*)d_in[30];
    const float* d_bb2 = (const float*)d_in[31];
    const float* d_g3 = (const float*)d_in[32];
    const float* d_b3 = (const float*)d_in[33];
    (void)in_sizes; (void)n_in; (void)out_size; (void)ws_size;

    const int M = BB * SS;          // 4096
    const int NSD = SS * DD;        // 262144
    const int NTOK = BB * SS * DD;  // 2097152
    const size_t WSZ = (size_t)DD * 512;  // 262144 (one 512x512 weight)

    float* ws = (float*)d_ws;
    float* pe = ws;
    float* x  = pe + NSD;
    float* y  = x + NTOK;
    float* t0 = y + NTOK;
    ushort* xbf  = (ushort*)(t0 + NTOK);
    ushort* ybf  = xbf + NTOK;
    ushort* qkvb = ybf + NTOK;              // M x 1536 packed QKV
    ushort* ob   = qkvb + (size_t)M * 1536;
    ushort* wt   = ob + NTOK;               // 1M bf16 transposed-weight scratch
    ushort* hbf  = qkvb;                    // FFN hidden 4096x2048 aliases qkvb+ob

    pe_k<<<SS, 256, 0, stream>>>(pe);
    add_pe_k<<<NTOK / 4 / 256, 256, 0, stream>>>(src_seq, pe, x, xbf);
    add_pe_k<<<NTOK / 4 / 256, 256, 0, stream>>>(trg_seq, pe, y, ybf);

    auto do_mha = [&](float* statef, ushort* statebf, const ushort* kvbf,
                      const float* wq, const float* wk, const float* wv, const float* wo,
                      const float* g, const float* bb, const int* pad) {
        tcast_k<<<dim3(8, 8, 4), 256, 0, stream>>>(wq, wk, wv, wo, wt, 512, 512);
        if (kvbf == statebf) {
            // packed QKV in one GEMM: Bt rows 0..1535 = [wq^T | wk^T | wv^T]
            gemm2_k<false, false, false, true><<<32 * 24, 256, 0, stream>>>(
                statebf, wt, nullptr, nullptr, qkvb, M, 1536, 512, 24);
        } else {
            // cross-attn: Q from statebf, K/V from kvbf
            gemm2_k<false, false, false, true><<<32 * 8, 256, 0, stream>>>(
                statebf, wt + 0 * WSZ, nullptr, nullptr, qkvb, M, 1536, 512, 8);
            gemm2_k<false, false, false, true><<<32 * 16, 256, 0, stream>>>(
                kvbf, wt + 1 * WSZ, nullptr, nullptr, qkvb + DD, M, 1536, 512, 16);
        }
        attn_k<<<dim3(SS / 64, HH, BB), 256, 0, stream>>>(qkvb, ob, pad);
        gemm2_k<false, true, false, false><<<32 * 8, 256, 0, stream>>>(
            ob, wt + 3 * WSZ, nullptr, statef, t0, M, 512, 512, 8);
        ln_k<<<M, 256, 0, stream>>>(t0, g, bb, statef, statebf);
    };
    auto do_ffn = [&](float* statef, ushort* statebf,
                      const float* w1, const float* b1, const float* w2, const float* b2,
                      const float* g, const float* bb) {
        tcast_k<<<dim3(32, 8, 1), 256, 0, stream>>>(w1, w1, w1, w1, wt, 512, DFFv);
        gemm2_k<true, false, true, true><<<32 * 32, 256, 0, stream>>>(
            statebf, wt, b1, nullptr, hbf, M, DFFv, 512, 32);
        tcast_k<<<dim3(8, 32, 1), 256, 0, stream>>>(w2, w2, w2, w2, wt, DFFv, 512);
        gemm2_k<true, true, false, false><<<32 * 8, 256, 0, stream>>>(
            hbf, wt, b2, statef, t0, M, 512, DFFv, 8);
        ln_k<<<M, 256, 0, stream>>>(t0, g, bb, statef, statebf);
    };

    for (int l = 0; l < LL; ++l) {
        do_mha(x, xbf, xbf,
               e_wq + (size_t)l * DD * 512, e_wk + (size_t)l * DD * 512,
               e_wv + (size_t)l * DD * 512, e_wo + (size_t)l * 512 * DD,
               e_g1 + l * DD, e_b1 + l * DD, enc_pad);
        do_ffn(x, xbf, e_w1 + (size_t)l * DD * DFFv, e_bb1 + l * DFFv,
               e_w2 + (size_t)l * DFFv * DD, e_bb2 + l * DD,
               e_g2 + l * DD, e_b2 + l * DD);
    }
    for (int l = 0; l < LL; ++l) {
        do_mha(y, ybf, ybf,
               d_swq + (size_t)l * DD * 512, d_swk + (size_t)l * DD * 512,
               d_swv + (size_t)l * DD * 512, d_swo + (size_t)l * 512 * DD,
               d_g1 + l * DD, d_b1 + l * DD, dec_pad);
        do_mha(y, ybf, xbf,
               d_cwq + (size_t)l * DD * 512, d_cwk + (size_t)l * DD * 512,
               d_cwv + (size_t)l * DD * 512, d_cwo + (size_t)l * 512 * DD,
               d_g2 + l * DD, d_b2 + l * DD, enc_pad);
        do_ffn(y, ybf, d_w1 + (size_t)l * DD * DFFv, d_bb1 + l * DFFv,
               d_w2 + (size_t)l * DFFv * DD, d_bb2 + l * DD,
               d_g3 + l * DD, d_b3 + l * DD);
    }

    copy_k<<<NTOK / 4 / 256, 256, 0, stream>>>(y, (float*)d_out);
}

// Round 6
// 668.381 us; speedup vs baseline: 8.1493x; 1.0774x over previous
//
#include <hip/hip_runtime.h>
#include <hip/hip_bf16.h>

// Problem constants
#define BB 8
#define SS 512
#define DD 512
#define HH 8
#define DQKv 64
#define DFFv 2048
#define LL 2

typedef __attribute__((ext_vector_type(8))) __bf16 bf16x8;
typedef __attribute__((ext_vector_type(4))) float f32x4;

// fp32 -> bf16 (RNE), bf16 -> fp32 helpers on raw ushort bits
static __device__ __forceinline__ ushort f2b(float x) {
    unsigned int u = __float_as_uint(x);
    unsigned int r = (u + 0x7FFFu + ((u >> 16) & 1u)) >> 16;
    return (ushort)r;
}
static __device__ __forceinline__ float b2f(ushort u) {
    return __uint_as_float(((unsigned int)u) << 16);
}

typedef __attribute__((address_space(1))) const unsigned int gas_u32;
typedef __attribute__((address_space(3))) unsigned int las_u32;
static __device__ __forceinline__ void gload16(const void* g, void* l) {
    __builtin_amdgcn_global_load_lds((gas_u32*)g, (las_u32*)l, 16, 0, 0);
}

// ---------------------------------------------------------------------------
// x = in + PE (PE trig computed inline, same fp32 math as reference);
// handles src->x and trg->y in one grid. Writes fp32 + bf16 copies.
// ---------------------------------------------------------------------------
__global__ __launch_bounds__(256) void add_pe2_k(const float* __restrict__ src,
                                                 const float* __restrict__ trg,
                                                 float* __restrict__ xf,
                                                 ushort* __restrict__ xb,
                                                 float* __restrict__ yf,
                                                 ushort* __restrict__ yb) {
    const int NQ = BB * SS * DD / 4;
    int i = blockIdx.x * 256 + threadIdx.x;       // 0 .. 2*NQ-1
    const bool second = i >= NQ;
    const int ii = second ? i - NQ : i;
    const int rem = ii & (SS * DD / 4 - 1);
    const int d4 = rem & (DD / 4 - 1);            // 0..127
    const int s = rem >> 7;

    float4 a = ((const float4*)(second ? trg : src))[ii];
    const float c = -9.210340371976184f / 512.0f; // -ln(1e4)/D
    const float div0 = __expf((float)(4 * d4) * c);
    const float div1 = __expf((float)(4 * d4 + 2) * c);
    const float a0 = (float)s * div0, a1 = (float)s * div1;
    a.x += sinf(a0); a.y += cosf(a0);
    a.z += sinf(a1); a.w += cosf(a1);

    float* of = second ? yf : xf;
    ushort* ob = second ? yb : xb;
    ((float4*)of)[ii] = a;
    ushort4 ub;
    ub.x = f2b(a.x); ub.y = f2b(a.y); ub.z = f2b(a.z); ub.w = f2b(a.w);
    ((ushort4*)ob)[ii] = ub;
}

// ---------------------------------------------------------------------------
// Per-op weight transpose+cast (fallback when ws is small):
// src (K x N fp32, pick by blockIdx.z) -> dst (N x K bf16)
// ---------------------------------------------------------------------------
__global__ __launch_bounds__(256) void tcast_k(const float* __restrict__ s0,
                                               const float* __restrict__ s1,
                                               const float* __restrict__ s2,
                                               const float* __restrict__ s3,
                                               ushort* __restrict__ dst,
                                               int K, int N) {
    __shared__ ushort st[64][72];
    const float* src = (blockIdx.z == 0) ? s0 : (blockIdx.z == 1) ? s1
                     : (blockIdx.z == 2) ? s2 : s3;
    ushort* d = dst + (size_t)blockIdx.z * K * N;
    const int k0 = blockIdx.y * 64, n0 = blockIdx.x * 64;
    const int t = threadIdx.x;
    const int r = t >> 2, c4 = (t & 3) * 16;
#pragma unroll
    for (int i = 0; i < 16; i += 4) {
        float4 v = *(const float4*)&src[(size_t)(k0 + r) * N + n0 + c4 + i];
        st[c4 + i + 0][r] = f2b(v.x);
        st[c4 + i + 1][r] = f2b(v.y);
        st[c4 + i + 2][r] = f2b(v.z);
        st[c4 + i + 3][r] = f2b(v.w);
    }
    __syncthreads();
    const int n = t >> 2, seg = (t & 3) * 16;
    *(uint4*)&d[(size_t)(n0 + n) * K + k0 + seg]     = *(const uint4*)&st[n][seg];
    *(uint4*)&d[(size_t)(n0 + n) * K + k0 + seg + 8] = *(const uint4*)&st[n][seg + 8];
}

// ---------------------------------------------------------------------------
// All-weights transpose+cast in ONE launch. Table passed by value.
// ---------------------------------------------------------------------------
#define NW 32
struct WTab {
    const float* src[NW];
    unsigned off[NW];   // dst offset in ushort elems
    int Kd[NW];         // K/64
    int Nd[NW];         // N/64
    int cum[NW + 1];    // tile prefix sums
};

__global__ __launch_bounds__(256) void tcast_all_k(WTab tab, ushort* __restrict__ dst) {
    __shared__ ushort st[64][72];
    const int t = blockIdx.x;
    int m = 0;
    while (t >= tab.cum[m + 1]) ++m;
    const int local = t - tab.cum[m];
    const int ntx = tab.Nd[m];
    const int bx = local % ntx, by = local / ntx;
    const float* src = tab.src[m];
    ushort* d = dst + tab.off[m];
    const int N = ntx * 64, K = tab.Kd[m] * 64;
    const int k0 = by * 64, n0 = bx * 64;

    const int tt = threadIdx.x;
    const int r = tt >> 2, c4 = (tt & 3) * 16;
#pragma unroll
    for (int i = 0; i < 16; i += 4) {
        float4 v = *(const float4*)&src[(size_t)(k0 + r) * N + n0 + c4 + i];
        st[c4 + i + 0][r] = f2b(v.x);
        st[c4 + i + 1][r] = f2b(v.y);
        st[c4 + i + 2][r] = f2b(v.z);
        st[c4 + i + 3][r] = f2b(v.w);
    }
    __syncthreads();
    const int n = tt >> 2, seg = (tt & 3) * 16;
    *(uint4*)&d[(size_t)(n0 + n) * K + k0 + seg]     = *(const uint4*)&st[n][seg];
    *(uint4*)&d[(size_t)(n0 + n) * K + k0 + seg + 8] = *(const uint4*)&st[n][seg + 8];
}

// ---------------------------------------------------------------------------
// bf16 MFMA GEMM, m97-style: C(M,N) = A(M,K) @ Bt(N,K)^T [+bias][+res][relu]
// BM=128, BN=64, BK=64. 256 threads = 4 waves (2x2), wave does 64x32 via
// 4x2 16x16x32 frags. Staging via global_load_lds width 16 (linear LDS).
// 1D grid = (M/128)*(N/64) with bijective XCD swizzle (grid % 8 == 0).
// ---------------------------------------------------------------------------
template <bool BIAS, bool RES, bool RELU, bool OUTBF>
__global__ __launch_bounds__(256) void gemm2_k(const ushort* __restrict__ A,
                                               const ushort* __restrict__ Bt,
                                               const float* __restrict__ bias,
                                               const float* __restrict__ res,
                                               void* __restrict__ Cout,
                                               int M, int N, int K, int nbx) {
    __shared__ ushort sA[128 * 64];
    __shared__ ushort sB[64 * 64];

    const int tid = threadIdx.x;
    const int nwg = gridDim.x;
    const int wg = blockIdx.x;
    const int swz = (wg & 7) * (nwg >> 3) + (wg >> 3);   // XCD-contiguous chunks
    const int bx = swz % nbx, by = swz / nbx;

    const int lane = tid & 63, w = tid >> 6;
    const int wm = w >> 1, wn = w & 1;
    const int llo = lane & 15, lhi = lane >> 4;

    const int srow = tid >> 3;           // 0..31
    const int scol = (tid & 7) * 8;      // element offset in row (8 elems=16B)
    const ushort* Ab = A + (size_t)(by * 128 + srow) * K + scol;
    const ushort* Bb = Bt + (size_t)(bx * 64 + srow) * K + scol;
    char* sAd = (char*)sA + srow * 128 + (tid & 7) * 16;
    char* sBd = (char*)sB + srow * 128 + (tid & 7) * 16;

    f32x4 acc[4][2] = {};

    for (int k0 = 0; k0 < K; k0 += 64) {
#pragma unroll
        for (int i = 0; i < 4; ++i)
            gload16(Ab + (size_t)i * 32 * K + k0, sAd + i * 32 * 128);
#pragma unroll
        for (int i = 0; i < 2; ++i)
            gload16(Bb + (size_t)i * 32 * K + k0, sBd + i * 32 * 128);
        __syncthreads();   // drains vmcnt before barrier

#pragma unroll
        for (int ks = 0; ks < 2; ++ks) {
            bf16x8 af[4];
#pragma unroll
            for (int fa = 0; fa < 4; ++fa)
                af[fa] = *(const bf16x8*)&sA[(wm * 64 + fa * 16 + llo) * 64 + ks * 32 + lhi * 8];
            bf16x8 bfrag[2];
#pragma unroll
            for (int fb = 0; fb < 2; ++fb)
                bfrag[fb] = *(const bf16x8*)&sB[(wn * 32 + fb * 16 + llo) * 64 + ks * 32 + lhi * 8];
#pragma unroll
            for (int fa = 0; fa < 4; ++fa)
#pragma unroll
                for (int fb = 0; fb < 2; ++fb)
                    acc[fa][fb] = __builtin_amdgcn_mfma_f32_16x16x32_bf16(
                        af[fa], bfrag[fb], acc[fa][fb], 0, 0, 0);
        }
        __syncthreads();   // all reads done before next stage
    }

    // Epilogue. C/D frag: col = lane&15, row = (lane>>4)*4 + j
#pragma unroll
    for (int fa = 0; fa < 4; ++fa) {
#pragma unroll
        for (int fb = 0; fb < 2; ++fb) {
            const int col = bx * 64 + wn * 32 + fb * 16 + llo;
            const float bv = BIAS ? bias[col] : 0.f;
#pragma unroll
            for (int j = 0; j < 4; ++j) {
                const int row = by * 128 + wm * 64 + fa * 16 + lhi * 4 + j;
                float v = acc[fa][fb][j] + bv;
                if (RES) v += res[(size_t)row * N + col];
                if (RELU) v = fmaxf(v, 0.f);
                if (OUTBF) ((ushort*)Cout)[(size_t)row * N + col] = f2b(v);
                else       ((float*)Cout)[(size_t)row * N + col] = v;
            }
        }
    }
}

// ---------------------------------------------------------------------------
// MFMA flash attention on packed QKV [M][1536] (Q cols 0-511, K 512-1023,
// V 1024-1535; head h at h*64 within segment). One block per (b,h,64 q-rows),
// 4 waves, wave owns 16 q-rows. Window masks, klim, all-masked-uniform
// fallback — semantics verified R2-R5.
// ---------------------------------------------------------------------------
__global__ __launch_bounds__(256) void attn_k(const ushort* __restrict__ QKV,
                                              ushort* __restrict__ O,
                                              const int* __restrict__ pad) {
    __shared__ ushort sQ[64][72];
    __shared__ ushort sK[64][72];
    __shared__ ushort sVt[64][72];   // V transposed: [d][key]
    __shared__ ushort sP[64][72];    // P: [q][key-local]

    const int tid = threadIdx.x;
    const int b = blockIdx.z, h = blockIdx.y, q0 = blockIdx.x << 6;
    const int klim = SS - pad[b];
    const int lane = tid & 63, w = tid >> 6;
    const int qw0 = w << 4;
    const int lhi = lane >> 4, llo = lane & 15;
    const int ST = 3 * DD;           // 1536 row stride

    // ---- stage Q tile ----
    {
        const int r = tid >> 2, seg = (tid & 3) << 4;
        const ushort* src = &QKV[(size_t)(b * SS + q0 + r) * ST + h * DQKv + seg];
        *(uint4*)&sQ[r][seg]     = *(const uint4*)src;
        *(uint4*)&sQ[r][seg + 8] = *(const uint4*)(src + 8);
    }

    auto window = [&](int i, int& wlo, int& whi) {
        if (h < 6) {
            const int step = 4 << (h >> 1);
            const int s2 = step >> 1;
            const int a1 = (i < s2) ? i : s2;
            const int a2 = ((SS - 1 - i) < s2) ? (SS - 1 - i) : s2;
            const int left = (i < SS / 2) ? a1 : (step - a2);
            wlo = i - left;
            whi = wlo + step;
        } else {
            wlo = 0;
            whi = SS - 1;
        }
    };

    int lo[4], hi[4];
#pragma unroll
    for (int j = 0; j < 4; ++j) window(q0 + qw0 + lhi * 4 + j, lo[j], hi[j]);

    int kt0 = 0, kt1 = SS;
    if (h < 6) {
        int lo0, hi0, lo63, hi63;
        window(q0, lo0, hi0);
        window(q0 + 63, lo63, hi63);
        if (lo63 >= klim) {
            kt0 = 0; kt1 = SS;
        } else {
            kt0 = (lo0 >> 6) << 6;
            kt1 = ((hi63 >> 6) + 1) << 6;
            if (kt1 > SS) kt1 = SS;
        }
    }

    float mr[4] = {-1e30f, -1e30f, -1e30f, -1e30f};
    float lr[4] = {0.f, 0.f, 0.f, 0.f};
    f32x4 oacc[4] = {};

    for (int kt = kt0; kt < kt1; kt += 64) {
        __syncthreads();
        {
            const int r = tid >> 2, seg = (tid & 3) << 4;
            const ushort* ksrc = &QKV[(size_t)(b * SS + kt + r) * ST + DD + h * DQKv + seg];
            *(uint4*)&sK[r][seg]     = *(const uint4*)ksrc;
            *(uint4*)&sK[r][seg + 8] = *(const uint4*)(ksrc + 8);
            const ushort* vsrc = &QKV[(size_t)(b * SS + kt + r) * ST + 2 * DD + h * DQKv + seg];
            uint4 u0 = *(const uint4*)vsrc;
            uint4 u1 = *(const uint4*)(vsrc + 8);
            const ushort* v0 = (const ushort*)&u0;
            const ushort* v1 = (const ushort*)&u1;
#pragma unroll
            for (int i = 0; i < 8; ++i) sVt[seg + i][r] = v0[i];
#pragma unroll
            for (int i = 0; i < 8; ++i) sVt[seg + 8 + i][r] = v1[i];
        }
        __syncthreads();

        // ---- QK^T ----
        f32x4 sacc[4] = {};
#pragma unroll
        for (int ks = 0; ks < 2; ++ks) {
            bf16x8 aq = *(const bf16x8*)&sQ[qw0 + llo][ks * 32 + lhi * 8];
#pragma unroll
            for (int n = 0; n < 4; ++n) {
                bf16x8 bk = *(const bf16x8*)&sK[n * 16 + llo][ks * 32 + lhi * 8];
                sacc[n] = __builtin_amdgcn_mfma_f32_16x16x32_bf16(aq, bk, sacc[n], 0, 0, 0);
            }
        }

        // ---- mask + scale + online softmax ----
#pragma unroll
        for (int j = 0; j < 4; ++j) {
            float s[4];
#pragma unroll
            for (int n = 0; n < 4; ++n) {
                const int kidx = kt + n * 16 + llo;
                const bool ok = (kidx < klim) && (kidx >= lo[j]) && (kidx <= hi[j]);
                s[n] = ok ? (sacc[n][j] * 0.125f) : -1e9f;
            }
            float tm = fmaxf(fmaxf(s[0], s[1]), fmaxf(s[2], s[3]));
#pragma unroll
            for (int off = 8; off; off >>= 1) tm = fmaxf(tm, __shfl_xor(tm, off));
            const float mn = fmaxf(mr[j], tm);
            const float alpha = __expf(mr[j] - mn);
            mr[j] = mn;
            float ps = 0.f;
            const int prow = qw0 + lhi * 4 + j;
#pragma unroll
            for (int n = 0; n < 4; ++n) {
                const ushort pb = f2b(__expf(s[n] - mn));
                sP[prow][n * 16 + llo] = pb;
                ps += b2f(pb);
            }
#pragma unroll
            for (int off = 8; off; off >>= 1) ps += __shfl_xor(ps, off);
            lr[j] = lr[j] * alpha + ps;
            oacc[0][j] *= alpha; oacc[1][j] *= alpha;
            oacc[2][j] *= alpha; oacc[3][j] *= alpha;
        }

        // ---- PV ----
#pragma unroll
        for (int ks = 0; ks < 2; ++ks) {
            bf16x8 ap = *(const bf16x8*)&sP[qw0 + llo][ks * 32 + lhi * 8];
#pragma unroll
            for (int n = 0; n < 4; ++n) {
                bf16x8 bv = *(const bf16x8*)&sVt[n * 16 + llo][ks * 32 + lhi * 8];
                oacc[n] = __builtin_amdgcn_mfma_f32_16x16x32_bf16(ap, bv, oacc[n], 0, 0, 0);
            }
        }
    }

    // ---- epilogue ----
#pragma unroll
    for (int j = 0; j < 4; ++j) {
        const float inv = 1.f / lr[j];
        const int q = q0 + qw0 + lhi * 4 + j;
#pragma unroll
        for (int n = 0; n < 4; ++n) {
            O[(size_t)(b * SS + q) * (HH * DQKv) + h * DQKv + n * 16 + llo] =
                f2b(oacc[n][j] * inv);
        }
    }
}

// ---------------------------------------------------------------------------
// LayerNorm over rows of 512; writes fp32 state + bf16 state copy
// ---------------------------------------------------------------------------
__global__ __launch_bounds__(256) void ln_k(const float* __restrict__ in,
                                            const float* __restrict__ g,
                                            const float* __restrict__ bvec,
                                            float* __restrict__ outf,
                                            ushort* __restrict__ outb) {
    const int row = blockIdx.x;
    const int tid = threadIdx.x;
    const float2 xv = *(const float2*)&in[(size_t)row * DD + tid * 2];

    __shared__ float red[4];
    __shared__ float red2[4];
    const int wid = tid >> 6, lane = tid & 63;

    float s = xv.x + xv.y;
#pragma unroll
    for (int off = 32; off; off >>= 1) s += __shfl_xor(s, off);
    if (lane == 0) red[wid] = s;
    __syncthreads();
    const float mu = (red[0] + red[1] + red[2] + red[3]) * (1.f / 512.f);

    const float dx = xv.x - mu, dy = xv.y - mu;
    float q = dx * dx + dy * dy;
#pragma unroll
    for (int off = 32; off; off >>= 1) q += __shfl_xor(q, off);
    if (lane == 0) red2[wid] = q;
    __syncthreads();
    const float var = (red2[0] + red2[1] + red2[2] + red2[3]) * (1.f / 512.f);
    const float rs = rsqrtf(var + 1e-6f);

    float2 o;
    o.x = dx * rs * g[tid * 2] + bvec[tid * 2];
    o.y = dy * rs * g[tid * 2 + 1] + bvec[tid * 2 + 1];
    *(float2*)&outf[(size_t)row * DD + tid * 2] = o;
    ushort2 ub; ub.x = f2b(o.x); ub.y = f2b(o.y);
    *(ushort2*)&outb[(size_t)row * DD + tid * 2] = ub;
}

// ---------------------------------------------------------------------------
// Host orchestration
// ---------------------------------------------------------------------------
extern "C" void kernel_launch(void* const* d_in, const int* in_sizes, int n_in,
                              void* d_out, int out_size, void* d_ws, size_t ws_size,
                              hipStream_t stream) {
    const float* src_seq = (const float*)d_in[0];
    const float* trg_seq = (const float*)d_in[1];
    const int* enc_pad = (const int*)d_in[2];
    const int* dec_pad = (const int*)d_in[3];
    const float* e_wq = (const float*)d_in[4];
    const float* e_wk = (const float*)d_in[5];
    const float* e_wv = (const float*)d_in[6];
    const float* e_wo = (const float*)d_in[7];
    const float* e_g1 = (const float*)d_in[8];
    const float* e_b1 = (const float*)d_in[9];
    const float* e_w1 = (const float*)d_in[10];
    const float* e_bb1 = (const float*)d_in[11];
    const float* e_w2 = (const float*)d_in[12];
    const float* e_bb2 = (const float*)d_in[13];
    const float* e_g2 = (const float*)d_in[14];
    const float* e_b2 = (const float*)d_in[15];
    const float* d_swq = (const float*)d_in[16];
    const float* d_swk = (const float*)d_in[17];
    const float* d_swv = (const float*)d_in[18];
    const float* d_swo = (const float*)d_in[19];
    const float* d_g1 = (const float*)d_in[20];
    const float* d_b1 = (const float*)d_in[21];
    const float* d_cwq = (const float*)d_in[22];
    const float* d_cwk = (const float*)d_in[23];
    const float* d_cwv = (const float*)d_in[24];
    const float* d_cwo = (const float*)d_in[25];
    const float* d_g2 = (const float*)d_in[26];
    const float* d_b2 = (const float*)d_in[27];
    const float* d_w1 = (const float*)d_in[28];
    const float* d_bb1 = (const float*)d_in[29];
    const float* d_w2 = (const float*)d_in[30];
    const float* d_bb2 = (const float*)d_in[31];
    const float* d_g3 = (const float*)d_in[32];
    const float* d_b3 = (const float*)d_in[33];
    (void)in_sizes; (void)n_in; (void)out_size;

    const int M = BB * SS;          // 4096
    const int NTOK = BB * SS * DD;  // 2097152
    const size_t WSZ = (size_t)DD * 512;  // 262144 elems (one 512x512 weight)

    float* ws = (float*)d_ws;
    float* x  = ws;
    float* y  = x + NTOK;
    float* t0 = y + NTOK;
    ushort* xbf  = (ushort*)(t0 + NTOK);
    ushort* ybf  = xbf + NTOK;
    ushort* qkvb = ybf + NTOK;              // M x 1536 packed QKV
    ushort* ob   = qkvb + (size_t)M * 1536;
    ushort* hbf  = qkvb;                    // FFN hidden 4096x2048 aliases qkvb+ob
    ushort* warena = ob + NTOK;             // big: all transposed weights; small: per-op scratch

    // ---- weight table (order must match forward-pass traversal) ----
    const float* wsrc[NW]; int wK[NW], wN[NW]; size_t woff[NW];
    int wcnt = 0; size_t acc = 0;
    auto push = [&](const float* p, int K, int N) {
        wsrc[wcnt] = p; wK[wcnt] = K; wN[wcnt] = N; woff[wcnt] = acc;
        acc += (size_t)K * N; ++wcnt;
    };
    for (int l = 0; l < LL; ++l) {
        push(e_wq + (size_t)l * WSZ, 512, 512);
        push(e_wk + (size_t)l * WSZ, 512, 512);
        push(e_wv + (size_t)l * WSZ, 512, 512);
        push(e_wo + (size_t)l * WSZ, 512, 512);
        push(e_w1 + (size_t)l * DD * DFFv, 512, DFFv);
        push(e_w2 + (size_t)l * DFFv * DD, DFFv, 512);
    }
    for (int l = 0; l < LL; ++l) {
        push(d_swq + (size_t)l * WSZ, 512, 512);
        push(d_swk + (size_t)l * WSZ, 512, 512);
        push(d_swv + (size_t)l * WSZ, 512, 512);
        push(d_swo + (size_t)l * WSZ, 512, 512);
        push(d_cwq + (size_t)l * WSZ, 512, 512);
        push(d_cwk + (size_t)l * WSZ, 512, 512);
        push(d_cwv + (size_t)l * WSZ, 512, 512);
        push(d_cwo + (size_t)l * WSZ, 512, 512);
        push(d_w1 + (size_t)l * DD * DFFv, 512, DFFv);
        push(d_w2 + (size_t)l * DFFv * DD, DFFv, 512);
    }

    const size_t base_bytes = (size_t)(warena - (ushort*)d_ws) * 2;  // up to arena
    const bool big = ws_size >= base_bytes + acc * 2;

    if (big) {
        WTab tab;
        int tiles = 0;
        for (int i = 0; i < NW; ++i) {
            tab.src[i] = wsrc[i];
            tab.off[i] = (unsigned)woff[i];
            tab.Kd[i] = wK[i] / 64;
            tab.Nd[i] = wN[i] / 64;
            tab.cum[i] = tiles;
            tiles += (wK[i] / 64) * (wN[i] / 64);
        }
        tab.cum[NW] = tiles;
        tcast_all_k<<<tiles, 256, 0, stream>>>(tab, warena);
    }

    add_pe2_k<<<2 * NTOK / 4 / 256, 256, 0, stream>>>(src_seq, trg_seq, x, xbf, y, ybf);

    // widx: index of this op's first matrix in the table
    auto do_mha = [&](float* statef, ushort* statebf, const ushort* kvbf, int widx,
                      const float* g, const float* bb, const int* pad) {
        const ushort* bt;
        if (big) {
            bt = warena + woff[widx];
        } else {
            tcast_k<<<dim3(8, 8, 4), 256, 0, stream>>>(
                wsrc[widx], wsrc[widx + 1], wsrc[widx + 2], wsrc[widx + 3],
                warena, 512, 512);
            bt = warena;
        }
        if (kvbf == statebf) {
            gemm2_k<false, false, false, true><<<32 * 24, 256, 0, stream>>>(
                statebf, bt, nullptr, nullptr, qkvb, M, 1536, 512, 24);
        } else {
            gemm2_k<false, false, false, true><<<32 * 8, 256, 0, stream>>>(
                statebf, bt + 0 * WSZ, nullptr, nullptr, qkvb, M, 1536, 512, 8);
            gemm2_k<false, false, false, true><<<32 * 16, 256, 0, stream>>>(
                kvbf, bt + 1 * WSZ, nullptr, nullptr, qkvb + DD, M, 1536, 512, 16);
        }
        attn_k<<<dim3(SS / 64, HH, BB), 256, 0, stream>>>(qkvb, ob, pad);
        gemm2_k<false, true, false, false><<<32 * 8, 256, 0, stream>>>(
            ob, bt + 3 * WSZ, nullptr, statef, t0, M, 512, 512, 8);
        ln_k<<<M, 256, 0, stream>>>(t0, g, bb, statef, statebf);
    };
    auto do_ffn = [&](float* statef, ushort* statebf, int widx,
                      const float* b1, const float* b2,
                      const float* g, const float* bb, float* lnoutf) {
        const ushort* bt1;
        const ushort* bt2;
        if (big) {
            bt1 = warena + woff[widx];
            bt2 = warena + woff[widx + 1];
        } else {
            tcast_k<<<dim3(32, 8, 1), 256, 0, stream>>>(
                wsrc[widx], wsrc[widx], wsrc[widx], wsrc[widx], warena, 512, DFFv);
            bt1 = warena;
            bt2 = warena;   // second tcast overwrites after FFN1 consumed it
        }
        gemm2_k<true, false, true, true><<<32 * 32, 256, 0, stream>>>(
            statebf, bt1, b1, nullptr, hbf, M, DFFv, 512, 32);
        if (!big) {
            tcast_k<<<dim3(8, 32, 1), 256, 0, stream>>>(
                wsrc[widx + 1], wsrc[widx + 1], wsrc[widx + 1], wsrc[widx + 1],
                warena, DFFv, 512);
        }
        gemm2_k<true, true, false, false><<<32 * 8, 256, 0, stream>>>(
            hbf, bt2, b2, statef, t0, M, 512, DFFv, 8);
        ln_k<<<M, 256, 0, stream>>>(t0, g, bb, lnoutf, statebf);
    };

    for (int l = 0; l < LL; ++l) {
        do_mha(x, xbf, xbf, l * 6, e_g1 + l * DD, e_b1 + l * DD, enc_pad);
        do_ffn(x, xbf, l * 6 + 4, e_bb1 + l * DFFv, e_bb2 + l * DD,
               e_g2 + l * DD, e_b2 + l * DD, x);
    }
    for (int l = 0; l < LL; ++l) {
        do_mha(y, ybf, ybf, 12 + l * 10, d_g1 + l * DD, d_b1 + l * DD, dec_pad);
        do_mha(y, ybf, xbf, 12 + l * 10 + 4, d_g2 + l * DD, d_b2 + l * DD, enc_pad);
        const bool last = (l == LL - 1);
        do_ffn(y, ybf, 12 + l * 10 + 8, d_bb1 + l * DFFv, d_bb2 + l * DD,
               d_g3 + l * DD, d_b3 + l * DD, last ? (float*)d_out : y);
    }
}